// Round 7
// baseline (297.503 us; speedup 1.0000x reference)
//
#include <hip/hip_runtime.h>

// TransformerDecoderLayer: B=4,S=2048,D=512,H=8,DK=64,DFF=2048, fp32 in/out.
// R7 = R6 minus hipMemsetAsync (kmax zeroed in k_maskbits; suspected SDMA graph
// serialization ~74us) + TM=64 GEMM variant for N=512 shapes (2 blocks/CU).
// attn identical to R6 (86us, 0 conflicts).

typedef __bf16 bf16x8 __attribute__((ext_vector_type(8)));
typedef float f32x4 __attribute__((ext_vector_type(4)));
typedef unsigned short us4 __attribute__((ext_vector_type(4)));
typedef unsigned u32x4 __attribute__((ext_vector_type(4)));

__device__ __forceinline__ unsigned short f2bf(float f){
  unsigned u = __builtin_bit_cast(unsigned, f);
  u += 0x7fffu + ((u >> 16) & 1u);   // RNE
  return (unsigned short)(u >> 16);
}

__device__ __forceinline__ unsigned cvt_pk_bf16(float lo, float hi){
  unsigned r;
  asm("v_cvt_pk_bf16_f32 %0, %1, %2" : "=v"(r) : "v"(lo), "v"(hi));
  return r;
}
__device__ __forceinline__ void plswap32(unsigned &a, unsigned &b){
  asm volatile("v_permlane32_swap_b32 %0, %1" : "+v"(a), "+v"(b));
}
__device__ __forceinline__ void plswap16(unsigned &a, unsigned &b){
  asm volatile("v_permlane16_swap_b32 %0, %1" : "+v"(a), "+v"(b));
}

typedef const __attribute__((address_space(1))) void* gas_t;
typedef __attribute__((address_space(3))) void* las_t;
__device__ __forceinline__ void gl_lds16(const void* g, void* l){
  __builtin_amdgcn_global_load_lds((gas_t)g, (las_t)l, 16, 0, 0);
}

// ---------- f32 -> bf16 convert ----------
__global__ void k_f2b(const float* __restrict__ in, unsigned short* __restrict__ out, int n4){
  int i = blockIdx.x * 256 + threadIdx.x;
  if (i < n4){
    float4 v = reinterpret_cast<const float4*>(in)[i];
    us4 o = { f2bf(v.x), f2bf(v.y), f2bf(v.z), f2bf(v.w) };
    reinterpret_cast<us4*>(out)[i] = o;
  }
}

// ---------- weight transpose+convert: in[K][N] f32 -> out[N][K] bf16 ----------
__global__ void k_wtrans(const float* __restrict__ in, unsigned short* __restrict__ out, int K, int N){
  __shared__ float t[32][33];
  int k0 = blockIdx.x*32, n0 = blockIdx.y*32;
  int tx = threadIdx.x & 31, ty = threadIdx.x >> 5;
  #pragma unroll
  for (int r = 0; r < 4; ++r)
    t[ty + 8*r][tx] = in[(size_t)(k0 + ty + 8*r)*N + n0 + tx];
  __syncthreads();
  #pragma unroll
  for (int r = 0; r < 4; ++r)
    out[(size_t)(n0 + ty + 8*r)*K + k0 + tx] = f2bf(t[tx][ty + 8*r]);
}

// qkv weights [H,512,64] (x3) -> Wt_qkv[1536][512]
__global__ void k_wtrans_qkv(const float* __restrict__ qw, const float* __restrict__ kw,
                             const float* __restrict__ vw, unsigned short* __restrict__ out){
  __shared__ float t[32][33];
  int z = blockIdx.z, sel = z >> 3, h = z & 7;
  const float* in = (sel==0 ? qw : (sel==1 ? kw : vw)) + (size_t)h*512*64;
  unsigned short* o = out + ((size_t)(sel*512 + h*64)) * 512;
  int k0 = blockIdx.x*32, n0 = blockIdx.y*32;
  int tx = threadIdx.x & 31, ty = threadIdx.x >> 5;
  #pragma unroll
  for (int r = 0; r < 4; ++r)
    t[ty + 8*r][tx] = in[(size_t)(k0 + ty + 8*r)*64 + n0 + tx];
  __syncthreads();
  #pragma unroll
  for (int r = 0; r < 4; ++r)
    o[(size_t)(n0 + ty + 8*r)*512 + k0 + tx] = f2bf(t[tx][ty + 8*r]);
}

__global__ void k_bqkv(const float* __restrict__ qb, const float* __restrict__ kb,
                       const float* __restrict__ vb, float* __restrict__ out){
  int n = blockIdx.x*256 + threadIdx.x;
  if (n < 1536){ int sel = n >> 9, r = n & 511;
    out[n] = (sel==0 ? qb : (sel==1 ? kb : vb))[r]; }
}

// ---------- mask tile bitmap (also zeroes kmax[32]: runs before k_qknorm) ----------
__global__ __launch_bounds__(256) void k_maskbits(const int* __restrict__ mask,
    unsigned short* __restrict__ out, float* __restrict__ kmax){
  const int tid = threadIdx.x;
  const int bq = blockIdx.x;            // b*32 + qt64
  const int half = blockIdx.y;
  if (bq == 0 && half == 0 && tid < 32) kmax[tid] = 0.f;
  const int b = bq >> 5, qt = bq & 31;
  const int* base = mask + (size_t)b*2048*2048 + (size_t)(qt*64 + (tid>>4)*4)*2048 + (tid&15)*4;
  unsigned bits = 0;
  for (int i = 0; i < 16; ++i){
    const int* p = base + (half*16 + i)*64;
    int ok = 1;
    #pragma unroll
    for (int r = 0; r < 4; ++r){
      int4 v = *reinterpret_cast<const int4*>(p + (size_t)r*2048);
      ok &= (v.x!=0)&(v.y!=0)&(v.z!=0)&(v.w!=0);
    }
    bits |= (unsigned)ok << i;
  }
  #pragma unroll
  for (int o = 1; o < 64; o <<= 1) bits &= __shfl_xor(bits, o);
  __shared__ unsigned red[4];
  if ((tid & 63) == 0) red[tid >> 6] = bits;
  __syncthreads();
  if (tid == 0) out[bq*2 + half] = (unsigned short)(red[0]&red[1]&red[2]&red[3]);
}

// ---------- row norms: qn[row]=|Q_row|; kmax[bh]=max_row |K_row| (atomic) ----------
__global__ __launch_bounds__(256) void k_qknorm(const unsigned short* __restrict__ Qb,
    const unsigned short* __restrict__ Kb, float* __restrict__ qn, float* __restrict__ kmax){
  const int tid = threadIdx.x;
  const size_t row = (size_t)blockIdx.x*32 + (tid>>3);
  const int sub = tid & 7;
  uint4 uq = *reinterpret_cast<const uint4*>(Qb + row*64 + sub*8);
  float s = 0.f;
  #pragma unroll
  for (int i = 0; i < 4; ++i){
    unsigned w = (&uq.x)[i];
    float f0 = __builtin_bit_cast(float, w << 16);
    float f1 = __builtin_bit_cast(float, w & 0xffff0000u);
    s += f0*f0 + f1*f1;
  }
  s += __shfl_xor(s, 1); s += __shfl_xor(s, 2); s += __shfl_xor(s, 4);
  if (sub == 0) qn[row] = sqrtf(s);
  uint4 uk = *reinterpret_cast<const uint4*>(Kb + row*64 + sub*8);
  float s2 = 0.f;
  #pragma unroll
  for (int i = 0; i < 4; ++i){
    unsigned w = (&uk.x)[i];
    float f0 = __builtin_bit_cast(float, w << 16);
    float f1 = __builtin_bit_cast(float, w & 0xffff0000u);
    s2 += f0*f0 + f1*f1;
  }
  s2 += __shfl_xor(s2, 1); s2 += __shfl_xor(s2, 2); s2 += __shfl_xor(s2, 4);
  float m = sqrtf(s2);
  m = fmaxf(m, __shfl_xor(m, 8));
  m = fmaxf(m, __shfl_xor(m, 16));
  m = fmaxf(m, __shfl_xor(m, 32));
  if ((tid & 63) == 0) atomicMax((int*)kmax + (int)(row >> 11), __float_as_int(m));
}

// ---------- GEMM: C[M,N] = A[M,K](bf16) * Bt[N,K]^T (bf16) + bias ----------
// TM = 128 (4-row-slot waves) or 64 (grid doubles along M for N=512 shapes).
// XOR key (row>>1)&3 is invariant across both stagings (bits 1-2 of row).
template<int MODE, int TM>
__global__ __launch_bounds__(256, 3) void k_gemm(
    const unsigned short* __restrict__ A, const unsigned short* __restrict__ Bt,
    const float* __restrict__ bias, const float* __restrict__ resid,
    unsigned short* __restrict__ ob0, unsigned short* __restrict__ ob1, unsigned short* __restrict__ ob2,
    float* __restrict__ of, int M, int N, int K)
{
  constexpr int MI = TM / 32;
  __shared__ unsigned short As[TM*32];
  __shared__ unsigned short Bs[128*32];
  const int tid = threadIdx.x, lane = tid & 63, wid = tid >> 6;
  const int g = lane >> 4, lr = lane & 15;
  const int rowBase = blockIdx.x * TM, colBase = blockIdx.y * 128;
  const int wr = (wid >> 1) * (TM/2), wc = (wid & 1) * 64;
  const int gcol = ((lane & 3) ^ ((lane >> 3) & 3)) * 8;   // src chunk XOR (row>>1)&3
  const int rchunk = (g ^ ((lr >> 1) & 3)) * 8;
  const int srowA = (TM == 128) ? (wid*32 + (lane >> 2)) : (wid*16 + (lane >> 2));
  unsigned short* lA = (TM == 128) ? &As[wid*1024] : &As[wid*512];
  unsigned short* lB = &Bs[wid*1024];
  const unsigned short* pA = A + (size_t)(rowBase + srowA)*K + gcol;
  const unsigned short* pB = Bt + (size_t)(colBase + wid*32 + (lane >> 2))*K + gcol;
  f32x4 acc[MI][4] = {};
  for (int k0 = 0; k0 < K; k0 += 32){
    __syncthreads();
    gl_lds16(pA + k0, lA);
    if constexpr (TM == 128) gl_lds16(pA + (size_t)16*K + k0, lA + 512);
    gl_lds16(pB + k0, lB);
    gl_lds16(pB + (size_t)16*K + k0, lB + 512);
    __syncthreads();
    bf16x8 af[MI], bfr[4];
    #pragma unroll
    for (int mi = 0; mi < MI; ++mi) af[mi]  = *reinterpret_cast<const bf16x8*>(&As[(wr + mi*16 + lr)*32 + rchunk]);
    #pragma unroll
    for (int ni = 0; ni < 4; ++ni) bfr[ni] = *reinterpret_cast<const bf16x8*>(&Bs[(wc + ni*16 + lr)*32 + rchunk]);
    #pragma unroll
    for (int mi = 0; mi < MI; ++mi)
      #pragma unroll
      for (int ni = 0; ni < 4; ++ni)
        acc[mi][ni] = __builtin_amdgcn_mfma_f32_16x16x32_bf16(af[mi], bfr[ni], acc[mi][ni], 0, 0, 0);
  }
  float bv[4];
  #pragma unroll
  for (int ni = 0; ni < 4; ++ni) bv[ni] = bias[colBase + wc + ni*16 + lr];
  #pragma unroll
  for (int mi = 0; mi < MI; ++mi){
    #pragma unroll
    for (int ni = 0; ni < 4; ++ni){
      #pragma unroll
      for (int j = 0; j < 4; ++j){
        int m = rowBase + wr + mi*16 + g*4 + j;
        int n = colBase + wc + ni*16 + lr;
        float v = acc[mi][ni][j] + bv[ni];
        if constexpr (MODE == 0){
          int b = m >> 11, s = m & 2047;
          int sel = n >> 9, rr = n & 511, h = rr >> 6, e = rr & 63;
          size_t bh = (size_t)(b*8 + h);
          if (sel == 0)      ob0[(bh*2048 + s)*64 + e] = f2bf(v);
          else if (sel == 1) ob1[(bh*2048 + s)*64 + e] = f2bf(v);
          else               ob2[(bh*64 + e)*2048 + s] = f2bf(v);   // V transposed
        } else if constexpr (MODE == 1 || MODE == 3){
          of[(size_t)m*N + n] = v + resid[(size_t)m*N + n];
        } else {
          ob0[(size_t)m*N + n] = f2bf(v > 0.f ? v : 0.f);
        }
      }
    }
  }
}

// ---------- flash attention (R6-identical): swapped QK^T, 16 q/wave, grid (32,32) ----------
__global__ __launch_bounds__(256) void k_attn(
    const unsigned short* __restrict__ Qb, const unsigned short* __restrict__ Kb,
    const unsigned short* __restrict__ Vt, const int* __restrict__ mask,
    const unsigned* __restrict__ mbits_p, const float* __restrict__ qn,
    const float* __restrict__ kmax, unsigned short* __restrict__ ctx)
{
  __shared__ unsigned short Ks[2][4096];   // [64 rows][8 chunks of 8 shorts], chunk-XOR
  __shared__ unsigned short Vs[2][4096];
  const int tid = threadIdx.x, lane = tid & 63, wid = tid >> 6;
  const int g = lane >> 4, lr = lane & 15;
  const int qt = blockIdx.x, bh = blockIdx.y;
  const int b = bh >> 3, h = bh & 7;
  const int qw = qt * 64 + wid * 16;
  const unsigned mbits = mbits_p[b*32 + qt];
  const size_t mbase = (size_t)b * 2048 * 2048;
  const float SC = 0.18033688f;   // log2(e)/sqrt(64)

  const int srow8 = lane >> 3;
  const int schunk = (lane & 7) ^ (srow8 & 7);
  const unsigned short* kgb = Kb + (size_t)bh*2048*64 + ((size_t)(wid*16) + srow8)*64 + schunk*8;
  const unsigned short* vgb = Vt + (size_t)bh*64*2048 + ((size_t)(wid*16) + srow8)*2048 + schunk*8;

  #define STAGE(buf, t) do { \
    gl_lds16(kgb + (size_t)(t)*4096,        &Ks[buf][(wid*16)*64]);   \
    gl_lds16(kgb + (size_t)(t)*4096 + 512,  &Ks[buf][(wid*16+8)*64]); \
    gl_lds16(vgb + (size_t)(t)*64,          &Vs[buf][(wid*16)*64]);   \
    gl_lds16(vgb + (size_t)(t)*64 + 8*2048, &Vs[buf][(wid*16+8)*64]); \
  } while(0)

  STAGE(0, 0);

  bf16x8 b_q[2];
  {
    const unsigned short* qp = Qb + ((size_t)bh*2048 + qw + lr)*64;
    b_q[0] = *reinterpret_cast<const bf16x8*>(qp + g*8);
    b_q[1] = *reinterpret_cast<const bf16x8*>(qp + 32 + g*8);
  }
  const float mfix = qn[(size_t)bh*2048 + qw + lr] * kmax[bh] * SC;

  f32x4 acc[4] = {};
  float lp = 0.f;
  int cur = 0;
  __syncthreads();

  for (int kt = 0; kt < 32; ++kt){
    if (kt < 31) STAGE(cur^1, kt+1);
    const unsigned short* Kc = Ks[cur];
    const unsigned short* Vc = Vs[cur];
    f32x4 st[4] = {};
    #pragma unroll
    for (int mk = 0; mk < 4; ++mk)
      #pragma unroll
      for (int ks = 0; ks < 2; ++ks){
        bf16x8 kf = *reinterpret_cast<const bf16x8*>(
            &Kc[(mk*16 + lr)*64 + (((ks*4 + g) ^ (lr & 7)))*8]);
        st[mk] = __builtin_amdgcn_mfma_f32_16x16x32_bf16(kf, b_q[ks], st[mk], 0,0,0);
      }
    if (!((mbits >> kt) & 1)){
      const int kk0 = kt * 64;
      #pragma unroll
      for (int mk = 0; mk < 4; ++mk)
        #pragma unroll
        for (int j = 0; j < 4; ++j){
          int kg = kk0 + mk*16 + g*4 + j;
          if (mask[mbase + (size_t)(qw + lr)*2048 + kg] == 0) st[mk][j] = -3.0e30f;
        }
    }
    unsigned wrd[4][2];
    float psA = 0.f, psB = 0.f;
    #pragma unroll
    for (int mk = 0; mk < 4; ++mk){
      float p0 = exp2f(__builtin_fmaf(st[mk][0], SC, -mfix));
      float p1 = exp2f(__builtin_fmaf(st[mk][1], SC, -mfix));
      float p2 = exp2f(__builtin_fmaf(st[mk][2], SC, -mfix));
      float p3 = exp2f(__builtin_fmaf(st[mk][3], SC, -mfix));
      psA += p0 + p2; psB += p1 + p3;
      wrd[mk][0] = cvt_pk_bf16(p0, p1);
      wrd[mk][1] = cvt_pk_bf16(p2, p3);
    }
    lp += psA + psB;
    bf16x8 pw[2];
    #pragma unroll
    for (int ks = 0; ks < 2; ++ks){
      unsigned a0 = wrd[2*ks][0], b0 = wrd[2*ks+1][0];
      unsigned a1 = wrd[2*ks][1], b1 = wrd[2*ks+1][1];
      plswap32(a0, b0); plswap16(a0, b0);
      plswap32(a1, b1); plswap16(a1, b1);
      u32x4 pk = { a0, a1, b0, b1 };
      pw[ks] = __builtin_bit_cast(bf16x8, pk);
    }
    #pragma unroll
    for (int ks = 0; ks < 2; ++ks)
      #pragma unroll
      for (int ne = 0; ne < 4; ++ne){
        bf16x8 vf = *reinterpret_cast<const bf16x8*>(
            &Vc[(ne*16 + lr)*64 + (((ks*4 + g) ^ (lr & 7)))*8]);
        acc[ne] = __builtin_amdgcn_mfma_f32_16x16x32_bf16(vf, pw[ks], acc[ne], 0,0,0);
      }
    if (kt < 31){
      __syncthreads();
      cur ^= 1;
    }
  }
  #undef STAGE
  float l = lp;
  l += __shfl_xor(l, 16);
  l += __shfl_xor(l, 32);
  float inv = 1.f / l;
  int q = qw + lr;
  #pragma unroll
  for (int ne = 0; ne < 4; ++ne)
    #pragma unroll
    for (int j = 0; j < 4; ++j){
      int e = ne*16 + g*4 + j;
      ctx[((size_t)b*2048 + q)*512 + h*64 + e] = f2bf(acc[ne][j] * inv);
    }
}

// ---------- LayerNorm: wave per row of 512 ----------
__global__ __launch_bounds__(256) void k_ln(
    const float* __restrict__ in, const float* __restrict__ gma, const float* __restrict__ bta,
    float* __restrict__ of, unsigned short* __restrict__ ob)
{
  const int lane = threadIdx.x & 63, wid = threadIdx.x >> 6;
  const size_t row = (size_t)blockIdx.x * 4 + wid;
  const float* x = in + row * 512;
  const int e0 = lane * 8;
  float xv[8];
  *reinterpret_cast<float4*>(&xv[0]) = *reinterpret_cast<const float4*>(x + e0);
  *reinterpret_cast<float4*>(&xv[4]) = *reinterpret_cast<const float4*>(x + e0 + 4);
  float s = 0.f, ss = 0.f;
  #pragma unroll
  for (int i = 0; i < 8; ++i){ s += xv[i]; ss += xv[i]*xv[i]; }
  #pragma unroll
  for (int o = 1; o < 64; o <<= 1){ s += __shfl_xor(s, o); ss += __shfl_xor(ss, o); }
  float mu = s * (1.f/512.f);
  float var = ss * (1.f/512.f) - mu*mu;
  float rs = rsqrtf(var + 1e-5f);
  float gv[8], bv[8], y[8];
  *reinterpret_cast<float4*>(&gv[0]) = *reinterpret_cast<const float4*>(gma + e0);
  *reinterpret_cast<float4*>(&gv[4]) = *reinterpret_cast<const float4*>(gma + e0 + 4);
  *reinterpret_cast<float4*>(&bv[0]) = *reinterpret_cast<const float4*>(bta + e0);
  *reinterpret_cast<float4*>(&bv[4]) = *reinterpret_cast<const float4*>(bta + e0 + 4);
  #pragma unroll
  for (int i = 0; i < 8; ++i) y[i] = (xv[i]-mu)*rs*gv[i] + bv[i];
  *reinterpret_cast<float4*>(of + row*512 + e0)     = *reinterpret_cast<float4*>(&y[0]);
  *reinterpret_cast<float4*>(of + row*512 + e0 + 4) = *reinterpret_cast<float4*>(&y[4]);
  if (ob){
    us4 o0 = { f2bf(y[0]), f2bf(y[1]), f2bf(y[2]), f2bf(y[3]) };
    us4 o1 = { f2bf(y[4]), f2bf(y[5]), f2bf(y[6]), f2bf(y[7]) };
    *reinterpret_cast<us4*>(ob + row*512 + e0)     = o0;
    *reinterpret_cast<us4*>(ob + row*512 + e0 + 4) = o1;
  }
}

extern "C" void kernel_launch(void* const* d_in, const int* in_sizes, int n_in,
                              void* d_out, int out_size, void* d_ws, size_t ws_size,
                              hipStream_t stream)
{
  const float* src  = (const float*)d_in[0];
  const int*   mask = (const int*)d_in[1];
  const float* q_w  = (const float*)d_in[2];
  const float* q_b  = (const float*)d_in[3];
  const float* k_w  = (const float*)d_in[4];
  const float* k_b  = (const float*)d_in[5];
  const float* v_w  = (const float*)d_in[6];
  const float* v_b  = (const float*)d_in[7];
  const float* o_w  = (const float*)d_in[8];
  const float* o_b  = (const float*)d_in[9];
  const float* ln1g = (const float*)d_in[10];
  const float* ln1b = (const float*)d_in[11];
  const float* w1   = (const float*)d_in[12];
  const float* b1   = (const float*)d_in[13];
  const float* w2   = (const float*)d_in[14];
  const float* b2   = (const float*)d_in[15];
  const float* ln2g = (const float*)d_in[16];
  const float* ln2b = (const float*)d_in[17];

  char* ws = (char*)d_ws;
  if (ws_size < 81795072) return;
  unsigned short* x_bf  = (unsigned short*)(ws + 0);          // 8.4MB (reused as LN1 bf16 out)
  unsigned short* wtqkv = (unsigned short*)(ws + 8388608);
  float*          bqkv  = (float*)(ws + 9961472);
  unsigned short* wto   = (unsigned short*)(ws + 9967616);
  unsigned short* wt1   = (unsigned short*)(ws + 10491904);
  unsigned short* wt2   = (unsigned short*)(ws + 12589056);
  unsigned short* Qb    = (unsigned short*)(ws + 14686208);
  unsigned short* Kb    = (unsigned short*)(ws + 23074816);
  unsigned short* Vt    = (unsigned short*)(ws + 31463424);
  unsigned short* ctx   = (unsigned short*)(ws + 39852032);
  unsigned short* ffb   = (unsigned short*)(ws + 14686208);   // overlays Q/K/Vt/ctx (dead by FF1)
  float* res = (float*)(ws + 48240640);                        // res1 then res2
  float* xf  = (float*)(ws + 65017856);
  // transients in res head (dead before gemm<1> writes res):
  unsigned short* mb16 = (unsigned short*)(ws + 48240640);     // 512B bitmap
  const unsigned* mb32 = (const unsigned*)(ws + 48240640);
  float* qn   = (float*)(ws + 48244736);                       // 256KB q-row norms
  float* kmax = (float*)(ws + 48506880);                       // 128B per-bh k max norm
  float* outf = (float*)d_out;

  k_maskbits<<<dim3(128,2), 256, 0, stream>>>(mask, mb16, kmax);
  k_f2b<<<4096, 256, 0, stream>>>(src, x_bf, 1048576);
  k_wtrans_qkv<<<dim3(16,2,24), 256, 0, stream>>>(q_w, k_w, v_w, wtqkv);
  k_bqkv<<<6, 256, 0, stream>>>(q_b, k_b, v_b, bqkv);
  k_wtrans<<<dim3(16,16), 256, 0, stream>>>(o_w, wto, 512, 512);
  k_wtrans<<<dim3(16,64), 256, 0, stream>>>(w1, wt1, 512, 2048);
  k_wtrans<<<dim3(64,16), 256, 0, stream>>>(w2, wt2, 2048, 512);

  k_gemm<0,128><<<dim3(64,12), 256, 0, stream>>>(x_bf, wtqkv, bqkv, nullptr,
                                                 Qb, Kb, Vt, nullptr, 8192, 1536, 512);
  k_qknorm<<<2048, 256, 0, stream>>>(Qb, Kb, qn, kmax);
  k_attn<<<dim3(32,32), 256, 0, stream>>>(Qb, Kb, Vt, mask, mb32, qn, kmax, ctx);
  k_gemm<1,64><<<dim3(128,4), 256, 0, stream>>>(ctx, wto, o_b, src,
                                                nullptr, nullptr, nullptr, res, 8192, 512, 512);
  k_ln<<<2048, 256, 0, stream>>>(res, ln1g, ln1b, xf, x_bf);
  k_gemm<2,128><<<dim3(64,16), 256, 0, stream>>>(x_bf, wt1, b1, nullptr,
                                                 ffb, nullptr, nullptr, nullptr, 8192, 2048, 512);
  k_gemm<3,64><<<dim3(128,4), 256, 0, stream>>>(ffb, wt2, b2, xf,
                                                nullptr, nullptr, nullptr, res, 8192, 512, 2048);
  k_ln<<<2048, 256, 0, stream>>>(res, ln2g, ln2b, outf, nullptr);
}

// Round 8
// 231.325 us; speedup vs baseline: 1.2861x; 1.2861x over previous
//
#include <hip/hip_runtime.h>

// TransformerDecoderLayer: B=4,S=2048,D=512,H=8,DK=64,DFF=2048, fp32 in/out.
// R8 = EXACT R2 skeleton (237us champion: same 14 launches, same GEMMs) with
// attn-internal upgrades only: XOR-swizzled K/V LDS (reg-staged, both sides),
// in-register P via cvt_pk+permlane (no P LDS), per-lane l partials.
// Online softmax + defer-max kept -> no qknorm/kmax kernels.

typedef __bf16 bf16x8 __attribute__((ext_vector_type(8)));
typedef float f32x4 __attribute__((ext_vector_type(4)));
typedef unsigned short us4 __attribute__((ext_vector_type(4)));
typedef unsigned u32x4 __attribute__((ext_vector_type(4)));

__device__ __forceinline__ unsigned short f2bf(float f){
  unsigned u = __builtin_bit_cast(unsigned, f);
  u += 0x7fffu + ((u >> 16) & 1u);   // RNE
  return (unsigned short)(u >> 16);
}

__device__ __forceinline__ unsigned cvt_pk_bf16(float lo, float hi){
  unsigned r;
  asm("v_cvt_pk_bf16_f32 %0, %1, %2" : "=v"(r) : "v"(lo), "v"(hi));
  return r;
}
__device__ __forceinline__ void plswap32(unsigned &a, unsigned &b){
  asm volatile("v_permlane32_swap_b32 %0, %1" : "+v"(a), "+v"(b));
}
__device__ __forceinline__ void plswap16(unsigned &a, unsigned &b){
  asm volatile("v_permlane16_swap_b32 %0, %1" : "+v"(a), "+v"(b));
}

typedef const __attribute__((address_space(1))) void* gas_t;
typedef __attribute__((address_space(3))) void* las_t;
__device__ __forceinline__ void gl_lds16(const void* g, void* l){
  __builtin_amdgcn_global_load_lds((gas_t)g, (las_t)l, 16, 0, 0);
}

// ---------- f32 -> bf16 convert (4 elems/thread) ----------
__global__ void k_f2b(const float* __restrict__ in, unsigned short* __restrict__ out, int n4){
  int i = blockIdx.x * 256 + threadIdx.x;
  if (i < n4){
    float4 v = reinterpret_cast<const float4*>(in)[i];
    us4 o = { f2bf(v.x), f2bf(v.y), f2bf(v.z), f2bf(v.w) };
    reinterpret_cast<us4*>(out)[i] = o;
  }
}

// ---------- weight transpose+convert: in[K][N] f32 -> out[N][K] bf16 ----------
__global__ void k_wtrans(const float* __restrict__ in, unsigned short* __restrict__ out, int K, int N){
  __shared__ float t[32][33];
  int k0 = blockIdx.x*32, n0 = blockIdx.y*32;
  int tx = threadIdx.x & 31, ty = threadIdx.x >> 5;
  #pragma unroll
  for (int r = 0; r < 4; ++r)
    t[ty + 8*r][tx] = in[(size_t)(k0 + ty + 8*r)*N + n0 + tx];
  __syncthreads();
  #pragma unroll
  for (int r = 0; r < 4; ++r)
    out[(size_t)(n0 + ty + 8*r)*K + k0 + tx] = f2bf(t[tx][ty + 8*r]);
}

// qkv weights [H,512,64] (x3) -> Wt_qkv[1536][512], row n = sel*512 + h*64 + e
__global__ void k_wtrans_qkv(const float* __restrict__ qw, const float* __restrict__ kw,
                             const float* __restrict__ vw, unsigned short* __restrict__ out){
  __shared__ float t[32][33];
  int z = blockIdx.z, sel = z >> 3, h = z & 7;
  const float* in = (sel==0 ? qw : (sel==1 ? kw : vw)) + (size_t)h*512*64;
  unsigned short* o = out + ((size_t)(sel*512 + h*64)) * 512;
  int k0 = blockIdx.x*32, n0 = blockIdx.y*32;
  int tx = threadIdx.x & 31, ty = threadIdx.x >> 5;
  #pragma unroll
  for (int r = 0; r < 4; ++r)
    t[ty + 8*r][tx] = in[(size_t)(k0 + ty + 8*r)*64 + n0 + tx];
  __syncthreads();
  #pragma unroll
  for (int r = 0; r < 4; ++r)
    o[(size_t)(n0 + ty + 8*r)*512 + k0 + tx] = f2bf(t[tx][ty + 8*r]);
}

__global__ void k_bqkv(const float* __restrict__ qb, const float* __restrict__ kb,
                       const float* __restrict__ vb, float* __restrict__ out){
  int n = blockIdx.x*256 + threadIdx.x;
  if (n < 1536){ int sel = n >> 9, r = n & 511;
    out[n] = (sel==0 ? qb : (sel==1 ? kb : vb))[r]; }
}

// ---------- mask tile bitmap: out16[b*32+qt][half] bit i = tile(qt, half*16+i) all-ones ----------
__global__ __launch_bounds__(256) void k_maskbits(const int* __restrict__ mask, unsigned short* __restrict__ out){
  const int tid = threadIdx.x;
  const int bq = blockIdx.x;            // b*32 + qt
  const int half = blockIdx.y;          // kt halves
  const int b = bq >> 5, qt = bq & 31;
  const int* base = mask + (size_t)b*2048*2048 + (size_t)(qt*64 + (tid>>4)*4)*2048 + (tid&15)*4;
  unsigned bits = 0;
  for (int i = 0; i < 16; ++i){
    const int* p = base + (half*16 + i)*64;
    int ok = 1;
    #pragma unroll
    for (int r = 0; r < 4; ++r){
      int4 v = *reinterpret_cast<const int4*>(p + (size_t)r*2048);
      ok &= (v.x!=0)&(v.y!=0)&(v.z!=0)&(v.w!=0);
    }
    bits |= (unsigned)ok << i;
  }
  #pragma unroll
  for (int o = 1; o < 64; o <<= 1) bits &= __shfl_xor(bits, o);
  __shared__ unsigned red[4];
  if ((tid & 63) == 0) red[tid >> 6] = bits;
  __syncthreads();
  if (tid == 0) out[bq*2 + half] = (unsigned short)(red[0]&red[1]&red[2]&red[3]);
}

// ---------- GEMM (R2-identical): C[M,N] = A[M,K] * Bt[N,K]^T + bias, fused epilogues ----------
// MODE 0: QKV scatter; 1: +resid f32 (O-proj); 2: bf16 relu (FF1); 3: +resid f32 (FF2)
template<int MODE>
__global__ __launch_bounds__(256, 3) void k_gemm(
    const unsigned short* __restrict__ A, const unsigned short* __restrict__ Bt,
    const float* __restrict__ bias, const float* __restrict__ resid,
    unsigned short* __restrict__ ob0, unsigned short* __restrict__ ob1, unsigned short* __restrict__ ob2,
    float* __restrict__ of, int M, int N, int K)
{
  __shared__ unsigned short As[128*32];   // linear [128][32]
  __shared__ unsigned short Bs[128*32];
  const int tid = threadIdx.x, lane = tid & 63, wid = tid >> 6;
  const int g = lane >> 4, lr = lane & 15;
  const int rowBase = blockIdx.x * 128, colBase = blockIdx.y * 128;
  const int wr = (wid >> 1) * 64, wc = (wid & 1) * 64;
  const int srow = wid*32 + (lane >> 2);
  const int gcol = ((lane & 3) ^ ((lane >> 3) & 3)) * 8;   // shorts
  const int rchunk = (g ^ ((lr >> 1) & 3)) * 8;
  unsigned short* lA = &As[wid*1024];
  unsigned short* lB = &Bs[wid*1024];
  const unsigned short* pA = A + (size_t)(rowBase + srow)*K + gcol;
  const unsigned short* pB = Bt + (size_t)(colBase + srow)*K + gcol;
  f32x4 acc[4][4] = {};
  for (int k0 = 0; k0 < K; k0 += 32){
    __syncthreads();
    gl_lds16(pA + k0, lA);
    gl_lds16(pA + (size_t)16*K + k0, lA + 512);
    gl_lds16(pB + k0, lB);
    gl_lds16(pB + (size_t)16*K + k0, lB + 512);
    __syncthreads();
    bf16x8 af[4], bfr[4];
    #pragma unroll
    for (int mi = 0; mi < 4; ++mi) af[mi]  = *reinterpret_cast<const bf16x8*>(&As[(wr + mi*16 + lr)*32 + rchunk]);
    #pragma unroll
    for (int ni = 0; ni < 4; ++ni) bfr[ni] = *reinterpret_cast<const bf16x8*>(&Bs[(wc + ni*16 + lr)*32 + rchunk]);
    #pragma unroll
    for (int mi = 0; mi < 4; ++mi)
      #pragma unroll
      for (int ni = 0; ni < 4; ++ni)
        acc[mi][ni] = __builtin_amdgcn_mfma_f32_16x16x32_bf16(af[mi], bfr[ni], acc[mi][ni], 0, 0, 0);
  }
  float bv[4];
  #pragma unroll
  for (int ni = 0; ni < 4; ++ni) bv[ni] = bias[colBase + wc + ni*16 + lr];
  #pragma unroll
  for (int mi = 0; mi < 4; ++mi){
    #pragma unroll
    for (int ni = 0; ni < 4; ++ni){
      #pragma unroll
      for (int j = 0; j < 4; ++j){
        int m = rowBase + wr + mi*16 + g*4 + j;
        int n = colBase + wc + ni*16 + lr;
        float v = acc[mi][ni][j] + bv[ni];
        if constexpr (MODE == 0){
          int b = m >> 11, s = m & 2047;
          int sel = n >> 9, rr = n & 511, h = rr >> 6, e = rr & 63;
          size_t bh = (size_t)(b*8 + h);
          if (sel == 0)      ob0[(bh*2048 + s)*64 + e] = f2bf(v);
          else if (sel == 1) ob1[(bh*2048 + s)*64 + e] = f2bf(v);
          else               ob2[(bh*64 + e)*2048 + s] = f2bf(v);   // V transposed
        } else if constexpr (MODE == 1 || MODE == 3){
          of[(size_t)m*N + n] = v + resid[(size_t)m*N + n];
        } else {
          ob0[(size_t)m*N + n] = f2bf(v > 0.f ? v : 0.f);
        }
      }
    }
  }
}

// ---------- flash attention: swapped QK^T, 16 q/wave, grid (32,32), online softmax ----------
// R2 staging structure (reg prefetch + 2 barriers/tile) with: XOR-swizzled K/V LDS
// (write chunk s^(r&7), read chunk (ks*4+g)^(lr&7)), cvt_pk+permlane in-register P,
// per-lane l partials, log2-domain defer-max.
__global__ __launch_bounds__(256) void k_attn(
    const unsigned short* __restrict__ Qb, const unsigned short* __restrict__ Kb,
    const unsigned short* __restrict__ Vt, const int* __restrict__ mask,
    const unsigned* __restrict__ mbits_p, unsigned short* __restrict__ ctx)
{
  __shared__ unsigned short Ks[64*64];   // [64 rows][8 chunks of 8 shorts], chunk-XOR layout
  __shared__ unsigned short Vs[64*64];
  const int tid = threadIdx.x, lane = tid & 63, wid = tid >> 6;
  const int g = lane >> 4, lr = lane & 15;
  const int qt = blockIdx.x, bh = blockIdx.y;
  const int b = bh >> 3, h = bh & 7;
  const int qw = qt * 64 + wid * 16;
  const unsigned mbits = mbits_p[b*32 + qt];
  const size_t mbase = (size_t)b * 2048 * 2048;
  const float SC = 0.18033688f;   // log2(e)/sqrt(64)

  bf16x8 b_q[2];   // Q as B-operand: col q = lr, k(e) = ks*32 + 8g + j
  {
    const unsigned short* qp = Qb + ((size_t)bh*2048 + qw + lr)*64;
    b_q[0] = *reinterpret_cast<const bf16x8*>(qp + g*8);
    b_q[1] = *reinterpret_cast<const bf16x8*>(qp + 32 + g*8);
  }
  f32x4 acc[4] = {};               // ctx^T frags: row e = ne*16+4g+j, col q = lr
  float m_run = -3.0e38f, lp = 0.f;

  // staging map: thread covers rows r0, r0+32 at chunk s; LDS chunk = s^(row&7)
  const int r0 = tid >> 3, s = tid & 7;
  const int wcol = (s ^ (r0 & 7)) * 8;            // (r0+32)&7 == r0&7
  const unsigned short* kp = Kb + (size_t)bh*2048*64 + (size_t)r0*64 + s*8;
  const unsigned short* vp = Vt + (size_t)bh*64*2048 + (size_t)r0*2048 + s*8;
  int4 kreg0, kreg1, vreg0, vreg1;

  kreg0 = *reinterpret_cast<const int4*>(kp);
  kreg1 = *reinterpret_cast<const int4*>(kp + 32*64);
  vreg0 = *reinterpret_cast<const int4*>(vp);
  vreg1 = *reinterpret_cast<const int4*>(vp + (size_t)32*2048);
  *reinterpret_cast<int4*>(&Ks[r0*64 + wcol])      = kreg0;
  *reinterpret_cast<int4*>(&Ks[(r0+32)*64 + wcol]) = kreg1;
  *reinterpret_cast<int4*>(&Vs[r0*64 + wcol])      = vreg0;
  *reinterpret_cast<int4*>(&Vs[(r0+32)*64 + wcol]) = vreg1;
  __syncthreads();

  for (int kt = 0; kt < 32; ++kt){
    if (kt < 31){   // prefetch next tile into regs (hides under compute)
      const unsigned short* kn = kp + (kt+1)*4096;
      const unsigned short* vn = vp + (kt+1)*64;
      kreg0 = *reinterpret_cast<const int4*>(kn);
      kreg1 = *reinterpret_cast<const int4*>(kn + 32*64);
      vreg0 = *reinterpret_cast<const int4*>(vn);
      vreg1 = *reinterpret_cast<const int4*>(vn + (size_t)32*2048);
    }
    // QK^T (swapped): A = K rows (k = mk*16+4g+j), B = Q (col q = lr)
    f32x4 st[4] = {};
    #pragma unroll
    for (int mk = 0; mk < 4; ++mk)
      #pragma unroll
      for (int ks = 0; ks < 2; ++ks){
        bf16x8 kf = *reinterpret_cast<const bf16x8*>(
            &Ks[(mk*16 + lr)*64 + (((ks*4 + g) ^ (lr & 7)))*8]);
        st[mk] = __builtin_amdgcn_mfma_f32_16x16x32_bf16(kf, b_q[ks], st[mk], 0,0,0);
      }
    if (!((mbits >> kt) & 1)){
      const int kk0 = kt * 64;
      #pragma unroll
      for (int mk = 0; mk < 4; ++mk)
        #pragma unroll
        for (int j = 0; j < 4; ++j){
          int kg = kk0 + mk*16 + g*4 + j;
          if (mask[mbase + (size_t)(qw + lr)*2048 + kg] == 0) st[mk][j] = -3.0e30f;
        }
    }
    // online softmax (log2 domain, scale folded); lane holds 16 values for q = lr
    float a0 = fmaxf(fmaxf(st[0][0], st[0][1]), fmaxf(st[0][2], st[0][3]));
    float a1 = fmaxf(fmaxf(st[1][0], st[1][1]), fmaxf(st[1][2], st[1][3]));
    float a2 = fmaxf(fmaxf(st[2][0], st[2][1]), fmaxf(st[2][2], st[2][3]));
    float a3 = fmaxf(fmaxf(st[3][0], st[3][1]), fmaxf(st[3][2], st[3][3]));
    float tm = fmaxf(fmaxf(a0, a1), fmaxf(a2, a3));
    tm = fmaxf(tm, __shfl_xor(tm, 16));
    tm = fmaxf(tm, __shfl_xor(tm, 32));
    float tms = tm * SC;
    if (!__all(tms <= m_run + 8.f)){   // defer-max, THR=8 (P bounded by 2^8)
      float mnew = fmaxf(m_run, tms);
      float alpha = exp2f(m_run - mnew);
      lp *= alpha;
      #pragma unroll
      for (int ne = 0; ne < 4; ++ne)
        #pragma unroll
        for (int j = 0; j < 4; ++j) acc[ne][j] *= alpha;
      m_run = mnew;
    }
    // P = exp2(S*SC - m_run); pack bf16 pairs; permlane exchange -> PV B-frags
    unsigned wrd[4][2];
    float psA = 0.f, psB = 0.f;
    #pragma unroll
    for (int mk = 0; mk < 4; ++mk){
      float p0 = exp2f(__builtin_fmaf(st[mk][0], SC, -m_run));
      float p1 = exp2f(__builtin_fmaf(st[mk][1], SC, -m_run));
      float p2 = exp2f(__builtin_fmaf(st[mk][2], SC, -m_run));
      float p3 = exp2f(__builtin_fmaf(st[mk][3], SC, -m_run));
      psA += p0 + p2; psB += p1 + p3;
      wrd[mk][0] = cvt_pk_bf16(p0, p1);
      wrd[mk][1] = cvt_pk_bf16(p2, p3);
    }
    lp += psA + psB;   // per-lane partial; reduced once at the end
    bf16x8 pw[2];
    #pragma unroll
    for (int ks = 0; ks < 2; ++ks){
      unsigned a0w = wrd[2*ks][0], b0w = wrd[2*ks+1][0];
      unsigned a1w = wrd[2*ks][1], b1w = wrd[2*ks+1][1];
      plswap32(a0w, b0w); plswap16(a0w, b0w);
      plswap32(a1w, b1w); plswap16(a1w, b1w);
      u32x4 pk = { a0w, a1w, b0w, b1w };
      pw[ks] = __builtin_bit_cast(bf16x8, pk);
    }
    // PV: ctx^T += Vt * P^T
    #pragma unroll
    for (int ks = 0; ks < 2; ++ks)
      #pragma unroll
      for (int ne = 0; ne < 4; ++ne){
        bf16x8 vf = *reinterpret_cast<const bf16x8*>(
            &Vs[(ne*16 + lr)*64 + (((ks*4 + g) ^ (lr & 7)))*8]);
        acc[ne] = __builtin_amdgcn_mfma_f32_16x16x32_bf16(vf, pw[ks], acc[ne], 0,0,0);
      }
    if (kt < 31){
      __syncthreads();   // all waves done reading Ks/Vs
      *reinterpret_cast<int4*>(&Ks[r0*64 + wcol])      = kreg0;
      *reinterpret_cast<int4*>(&Ks[(r0+32)*64 + wcol]) = kreg1;
      *reinterpret_cast<int4*>(&Vs[r0*64 + wcol])      = vreg0;
      *reinterpret_cast<int4*>(&Vs[(r0+32)*64 + wcol]) = vreg1;
      __syncthreads();   // staged tile visible
    }
  }
  float l = lp;
  l += __shfl_xor(l, 16);
  l += __shfl_xor(l, 32);
  float inv = 1.f / l;
  int q = qw + lr;
  #pragma unroll
  for (int ne = 0; ne < 4; ++ne){
    uint2 ow;
    ow.x = cvt_pk_bf16(acc[ne][0]*inv, acc[ne][1]*inv);
    ow.y = cvt_pk_bf16(acc[ne][2]*inv, acc[ne][3]*inv);
    *reinterpret_cast<uint2*>(&ctx[((size_t)b*2048 + q)*512 + h*64 + ne*16 + g*4]) = ow;
  }
}

// ---------- LayerNorm: wave per row of 512 ----------
__global__ __launch_bounds__(256) void k_ln(
    const float* __restrict__ in, const float* __restrict__ gma, const float* __restrict__ bta,
    float* __restrict__ of, unsigned short* __restrict__ ob)
{
  const int lane = threadIdx.x & 63, wid = threadIdx.x >> 6;
  const size_t row = (size_t)blockIdx.x * 4 + wid;
  const float* x = in + row * 512;
  const int e0 = lane * 8;
  float xv[8];
  *reinterpret_cast<float4*>(&xv[0]) = *reinterpret_cast<const float4*>(x + e0);
  *reinterpret_cast<float4*>(&xv[4]) = *reinterpret_cast<const float4*>(x + e0 + 4);
  float s = 0.f, ss = 0.f;
  #pragma unroll
  for (int i = 0; i < 8; ++i){ s += xv[i]; ss += xv[i]*xv[i]; }
  #pragma unroll
  for (int o = 1; o < 64; o <<= 1){ s += __shfl_xor(s, o); ss += __shfl_xor(ss, o); }
  float mu = s * (1.f/512.f);
  float var = ss * (1.f/512.f) - mu*mu;
  float rs = rsqrtf(var + 1e-5f);
  float gv[8], bv[8], y[8];
  *reinterpret_cast<float4*>(&gv[0]) = *reinterpret_cast<const float4*>(gma + e0);
  *reinterpret_cast<float4*>(&gv[4]) = *reinterpret_cast<const float4*>(gma + e0 + 4);
  *reinterpret_cast<float4*>(&bv[0]) = *reinterpret_cast<const float4*>(bta + e0);
  *reinterpret_cast<float4*>(&bv[4]) = *reinterpret_cast<const float4*>(bta + e0 + 4);
  #pragma unroll
  for (int i = 0; i < 8; ++i) y[i] = (xv[i]-mu)*rs*gv[i] + bv[i];
  *reinterpret_cast<float4*>(of + row*512 + e0)     = *reinterpret_cast<float4*>(&y[0]);
  *reinterpret_cast<float4*>(of + row*512 + e0 + 4) = *reinterpret_cast<float4*>(&y[4]);
  if (ob){
    us4 o0 = { f2bf(y[0]), f2bf(y[1]), f2bf(y[2]), f2bf(y[3]) };
    us4 o1 = { f2bf(y[4]), f2bf(y[5]), f2bf(y[6]), f2bf(y[7]) };
    *reinterpret_cast<us4*>(ob + row*512 + e0)     = o0;
    *reinterpret_cast<us4*>(ob + row*512 + e0 + 4) = o1;
  }
}

extern "C" void kernel_launch(void* const* d_in, const int* in_sizes, int n_in,
                              void* d_out, int out_size, void* d_ws, size_t ws_size,
                              hipStream_t stream)
{
  const float* src  = (const float*)d_in[0];
  const int*   mask = (const int*)d_in[1];
  const float* q_w  = (const float*)d_in[2];
  const float* q_b  = (const float*)d_in[3];
  const float* k_w  = (const float*)d_in[4];
  const float* k_b  = (const float*)d_in[5];
  const float* v_w  = (const float*)d_in[6];
  const float* v_b  = (const float*)d_in[7];
  const float* o_w  = (const float*)d_in[8];
  const float* o_b  = (const float*)d_in[9];
  const float* ln1g = (const float*)d_in[10];
  const float* ln1b = (const float*)d_in[11];
  const float* w1   = (const float*)d_in[12];
  const float* b1   = (const float*)d_in[13];
  const float* w2   = (const float*)d_in[14];
  const float* b2   = (const float*)d_in[15];
  const float* ln2g = (const float*)d_in[16];
  const float* ln2b = (const float*)d_in[17];

  char* ws = (char*)d_ws;
  if (ws_size < 81795072) return;
  unsigned short* x_bf  = (unsigned short*)(ws + 0);          // 8.4MB (reused as LN1 bf16 out)
  unsigned short* wtqkv = (unsigned short*)(ws + 8388608);
  float*          bqkv  = (float*)(ws + 9961472);
  unsigned short* wto   = (unsigned short*)(ws + 9967616);
  unsigned short* wt1   = (unsigned short*)(ws + 10491904);
  unsigned short* wt2   = (unsigned short*)(ws + 12589056);
  unsigned short* Qb    = (unsigned short*)(ws + 14686208);
  unsigned short* Kb    = (unsigned short*)(ws + 23074816);
  unsigned short* Vt    = (unsigned short*)(ws + 31463424);
  unsigned short* ctx   = (unsigned short*)(ws + 39852032);
  unsigned short* ffb   = (unsigned short*)(ws + 14686208);   // overlays Q/K/Vt/ctx (dead by FF1)
  float* res = (float*)(ws + 48240640);                        // res1 then res2
  float* xf  = (float*)(ws + 65017856);
  unsigned short* mb16 = (unsigned short*)(ws + 48240640);     // bitmap in res head (dead by gemm<1>)
  const unsigned* mb32 = (const unsigned*)(ws + 48240640);
  float* outf = (float*)d_out;

  k_maskbits<<<dim3(128,2), 256, 0, stream>>>(mask, mb16);
  k_f2b<<<4096, 256, 0, stream>>>(src, x_bf, 1048576);
  k_wtrans_qkv<<<dim3(16,2,24), 256, 0, stream>>>(q_w, k_w, v_w, wtqkv);
  k_bqkv<<<6, 256, 0, stream>>>(q_b, k_b, v_b, bqkv);
  k_wtrans<<<dim3(16,16), 256, 0, stream>>>(o_w, wto, 512, 512);
  k_wtrans<<<dim3(16,64), 256, 0, stream>>>(w1, wt1, 512, 2048);
  k_wtrans<<<dim3(64,16), 256, 0, stream>>>(w2, wt2, 2048, 512);

  k_gemm<0><<<dim3(64,12), 256, 0, stream>>>(x_bf, wtqkv, bqkv, nullptr,
                                             Qb, Kb, Vt, nullptr, 8192, 1536, 512);
  k_attn<<<dim3(32,32), 256, 0, stream>>>(Qb, Kb, Vt, mask, mb32, ctx);
  k_gemm<1><<<dim3(64,4), 256, 0, stream>>>(ctx, wto, o_b, src,
                                            nullptr, nullptr, nullptr, res, 8192, 512, 512);
  k_ln<<<2048, 256, 0, stream>>>(res, ln1g, ln1b, xf, x_bf);
  k_gemm<2><<<dim3(64,16), 256, 0, stream>>>(x_bf, wt1, b1, nullptr,
                                             ffb, nullptr, nullptr, nullptr, 8192, 2048, 512);
  k_gemm<3><<<dim3(64,4), 256, 0, stream>>>(ffb, wt2, b2, xf,
                                            nullptr, nullptr, nullptr, res, 8192, 512, 2048);
  k_ln<<<2048, 256, 0, stream>>>(res, ln2g, ln2b, outf, nullptr);
}

// Round 9
// 230.464 us; speedup vs baseline: 1.2909x; 1.0037x over previous
//
#include <hip/hip_runtime.h>

// TransformerDecoderLayer: B=4,S=2048,D=512,H=8,DK=64,DFF=2048, fp32 in/out.
// R9 = R8 (231us) with attn body swapped to: R6's gl_lds 2-buf staging flow
// (proven 86us, 0 conflicts, occ 31%) + R8's online softmax/defer-max +
// in-register P (cvt_pk+permlane) + T5 setprio around MFMA clusters.
// No qknorm (R5-R7 showed it costs ~70us in pipeline time). GEMMs/LN unchanged.

typedef __bf16 bf16x8 __attribute__((ext_vector_type(8)));
typedef float f32x4 __attribute__((ext_vector_type(4)));
typedef unsigned short us4 __attribute__((ext_vector_type(4)));
typedef unsigned u32x4 __attribute__((ext_vector_type(4)));

__device__ __forceinline__ unsigned short f2bf(float f){
  unsigned u = __builtin_bit_cast(unsigned, f);
  u += 0x7fffu + ((u >> 16) & 1u);   // RNE
  return (unsigned short)(u >> 16);
}

__device__ __forceinline__ unsigned cvt_pk_bf16(float lo, float hi){
  unsigned r;
  asm("v_cvt_pk_bf16_f32 %0, %1, %2" : "=v"(r) : "v"(lo), "v"(hi));
  return r;
}
__device__ __forceinline__ void plswap32(unsigned &a, unsigned &b){
  asm volatile("v_permlane32_swap_b32 %0, %1" : "+v"(a), "+v"(b));
}
__device__ __forceinline__ void plswap16(unsigned &a, unsigned &b){
  asm volatile("v_permlane16_swap_b32 %0, %1" : "+v"(a), "+v"(b));
}

typedef const __attribute__((address_space(1))) void* gas_t;
typedef __attribute__((address_space(3))) void* las_t;
__device__ __forceinline__ void gl_lds16(const void* g, void* l){
  __builtin_amdgcn_global_load_lds((gas_t)g, (las_t)l, 16, 0, 0);
}

// ---------- f32 -> bf16 convert (4 elems/thread) ----------
__global__ void k_f2b(const float* __restrict__ in, unsigned short* __restrict__ out, int n4){
  int i = blockIdx.x * 256 + threadIdx.x;
  if (i < n4){
    float4 v = reinterpret_cast<const float4*>(in)[i];
    us4 o = { f2bf(v.x), f2bf(v.y), f2bf(v.z), f2bf(v.w) };
    reinterpret_cast<us4*>(out)[i] = o;
  }
}

// ---------- weight transpose+convert: in[K][N] f32 -> out[N][K] bf16 ----------
__global__ void k_wtrans(const float* __restrict__ in, unsigned short* __restrict__ out, int K, int N){
  __shared__ float t[32][33];
  int k0 = blockIdx.x*32, n0 = blockIdx.y*32;
  int tx = threadIdx.x & 31, ty = threadIdx.x >> 5;
  #pragma unroll
  for (int r = 0; r < 4; ++r)
    t[ty + 8*r][tx] = in[(size_t)(k0 + ty + 8*r)*N + n0 + tx];
  __syncthreads();
  #pragma unroll
  for (int r = 0; r < 4; ++r)
    out[(size_t)(n0 + ty + 8*r)*K + k0 + tx] = f2bf(t[tx][ty + 8*r]);
}

// qkv weights [H,512,64] (x3) -> Wt_qkv[1536][512], row n = sel*512 + h*64 + e
__global__ void k_wtrans_qkv(const float* __restrict__ qw, const float* __restrict__ kw,
                             const float* __restrict__ vw, unsigned short* __restrict__ out){
  __shared__ float t[32][33];
  int z = blockIdx.z, sel = z >> 3, h = z & 7;
  const float* in = (sel==0 ? qw : (sel==1 ? kw : vw)) + (size_t)h*512*64;
  unsigned short* o = out + ((size_t)(sel*512 + h*64)) * 512;
  int k0 = blockIdx.x*32, n0 = blockIdx.y*32;
  int tx = threadIdx.x & 31, ty = threadIdx.x >> 5;
  #pragma unroll
  for (int r = 0; r < 4; ++r)
    t[ty + 8*r][tx] = in[(size_t)(k0 + ty + 8*r)*64 + n0 + tx];
  __syncthreads();
  #pragma unroll
  for (int r = 0; r < 4; ++r)
    o[(size_t)(n0 + ty + 8*r)*512 + k0 + tx] = f2bf(t[tx][ty + 8*r]);
}

__global__ void k_bqkv(const float* __restrict__ qb, const float* __restrict__ kb,
                       const float* __restrict__ vb, float* __restrict__ out){
  int n = blockIdx.x*256 + threadIdx.x;
  if (n < 1536){ int sel = n >> 9, r = n & 511;
    out[n] = (sel==0 ? qb : (sel==1 ? kb : vb))[r]; }
}

// ---------- mask tile bitmap: out16[b*32+qt][half] bit i = tile(qt, half*16+i) all-ones ----------
__global__ __launch_bounds__(256) void k_maskbits(const int* __restrict__ mask, unsigned short* __restrict__ out){
  const int tid = threadIdx.x;
  const int bq = blockIdx.x;            // b*32 + qt
  const int half = blockIdx.y;          // kt halves
  const int b = bq >> 5, qt = bq & 31;
  const int* base = mask + (size_t)b*2048*2048 + (size_t)(qt*64 + (tid>>4)*4)*2048 + (tid&15)*4;
  unsigned bits = 0;
  for (int i = 0; i < 16; ++i){
    const int* p = base + (half*16 + i)*64;
    int ok = 1;
    #pragma unroll
    for (int r = 0; r < 4; ++r){
      int4 v = *reinterpret_cast<const int4*>(p + (size_t)r*2048);
      ok &= (v.x!=0)&(v.y!=0)&(v.z!=0)&(v.w!=0);
    }
    bits |= (unsigned)ok << i;
  }
  #pragma unroll
  for (int o = 1; o < 64; o <<= 1) bits &= __shfl_xor(bits, o);
  __shared__ unsigned red[4];
  if ((tid & 63) == 0) red[tid >> 6] = bits;
  __syncthreads();
  if (tid == 0) out[bq*2 + half] = (unsigned short)(red[0]&red[1]&red[2]&red[3]);
}

// ---------- GEMM (R2-identical): C[M,N] = A[M,K] * Bt[N,K]^T + bias, fused epilogues ----------
// MODE 0: QKV scatter; 1: +resid f32 (O-proj); 2: bf16 relu (FF1); 3: +resid f32 (FF2)
template<int MODE>
__global__ __launch_bounds__(256, 3) void k_gemm(
    const unsigned short* __restrict__ A, const unsigned short* __restrict__ Bt,
    const float* __restrict__ bias, const float* __restrict__ resid,
    unsigned short* __restrict__ ob0, unsigned short* __restrict__ ob1, unsigned short* __restrict__ ob2,
    float* __restrict__ of, int M, int N, int K)
{
  __shared__ unsigned short As[128*32];   // linear [128][32]
  __shared__ unsigned short Bs[128*32];
  const int tid = threadIdx.x, lane = tid & 63, wid = tid >> 6;
  const int g = lane >> 4, lr = lane & 15;
  const int rowBase = blockIdx.x * 128, colBase = blockIdx.y * 128;
  const int wr = (wid >> 1) * 64, wc = (wid & 1) * 64;
  const int srow = wid*32 + (lane >> 2);
  const int gcol = ((lane & 3) ^ ((lane >> 3) & 3)) * 8;   // shorts
  const int rchunk = (g ^ ((lr >> 1) & 3)) * 8;
  unsigned short* lA = &As[wid*1024];
  unsigned short* lB = &Bs[wid*1024];
  const unsigned short* pA = A + (size_t)(rowBase + srow)*K + gcol;
  const unsigned short* pB = Bt + (size_t)(colBase + srow)*K + gcol;
  f32x4 acc[4][4] = {};
  for (int k0 = 0; k0 < K; k0 += 32){
    __syncthreads();
    gl_lds16(pA + k0, lA);
    gl_lds16(pA + (size_t)16*K + k0, lA + 512);
    gl_lds16(pB + k0, lB);
    gl_lds16(pB + (size_t)16*K + k0, lB + 512);
    __syncthreads();
    bf16x8 af[4], bfr[4];
    #pragma unroll
    for (int mi = 0; mi < 4; ++mi) af[mi]  = *reinterpret_cast<const bf16x8*>(&As[(wr + mi*16 + lr)*32 + rchunk]);
    #pragma unroll
    for (int ni = 0; ni < 4; ++ni) bfr[ni] = *reinterpret_cast<const bf16x8*>(&Bs[(wc + ni*16 + lr)*32 + rchunk]);
    #pragma unroll
    for (int mi = 0; mi < 4; ++mi)
      #pragma unroll
      for (int ni = 0; ni < 4; ++ni)
        acc[mi][ni] = __builtin_amdgcn_mfma_f32_16x16x32_bf16(af[mi], bfr[ni], acc[mi][ni], 0, 0, 0);
  }
  float bv[4];
  #pragma unroll
  for (int ni = 0; ni < 4; ++ni) bv[ni] = bias[colBase + wc + ni*16 + lr];
  #pragma unroll
  for (int mi = 0; mi < 4; ++mi){
    #pragma unroll
    for (int ni = 0; ni < 4; ++ni){
      #pragma unroll
      for (int j = 0; j < 4; ++j){
        int m = rowBase + wr + mi*16 + g*4 + j;
        int n = colBase + wc + ni*16 + lr;
        float v = acc[mi][ni][j] + bv[ni];
        if constexpr (MODE == 0){
          int b = m >> 11, s = m & 2047;
          int sel = n >> 9, rr = n & 511, h = rr >> 6, e = rr & 63;
          size_t bh = (size_t)(b*8 + h);
          if (sel == 0)      ob0[(bh*2048 + s)*64 + e] = f2bf(v);
          else if (sel == 1) ob1[(bh*2048 + s)*64 + e] = f2bf(v);
          else               ob2[(bh*64 + e)*2048 + s] = f2bf(v);   // V transposed
        } else if constexpr (MODE == 1 || MODE == 3){
          of[(size_t)m*N + n] = v + resid[(size_t)m*N + n];
        } else {
          ob0[(size_t)m*N + n] = f2bf(v > 0.f ? v : 0.f);
        }
      }
    }
  }
}

// ---------- flash attention: swapped QK^T, 16 q/wave, grid (32,32) ----------
// gl_lds chunk-XOR staging (2-buf, 1 barrier/tile, R6-proven), online softmax
// (log2 domain, defer-max), in-register P via cvt_pk+permlane, setprio on MFMA.
__global__ __launch_bounds__(256) void k_attn(
    const unsigned short* __restrict__ Qb, const unsigned short* __restrict__ Kb,
    const unsigned short* __restrict__ Vt, const int* __restrict__ mask,
    const unsigned* __restrict__ mbits_p, unsigned short* __restrict__ ctx)
{
  __shared__ unsigned short Ks[2][4096];   // [64 rows][8 chunks of 8 shorts], chunk-XOR
  __shared__ unsigned short Vs[2][4096];
  const int tid = threadIdx.x, lane = tid & 63, wid = tid >> 6;
  const int g = lane >> 4, lr = lane & 15;
  const int qt = blockIdx.x, bh = blockIdx.y;
  const int b = bh >> 3, h = bh & 7;
  const int qw = qt * 64 + wid * 16;
  const unsigned mbits = mbits_p[b*32 + qt];
  const size_t mbase = (size_t)b * 2048 * 2048;
  const float SC = 0.18033688f;   // log2(e)/sqrt(64)

  // staging map: lane covers LDS slot (row8 = lane>>3, chunk = lane&7);
  // global source chunk pre-XOR'd so LDS[r][c] = G[r][c^(r&7)].
  const int srow8 = lane >> 3;
  const int schunk = (lane & 7) ^ (srow8 & 7);
  const unsigned short* kgb = Kb + (size_t)bh*2048*64 + ((size_t)(wid*16) + srow8)*64 + schunk*8;
  const unsigned short* vgb = Vt + (size_t)bh*64*2048 + ((size_t)(wid*16) + srow8)*2048 + schunk*8;

  #define STAGE(buf, t) do { \
    gl_lds16(kgb + (size_t)(t)*4096,        &Ks[buf][(wid*16)*64]);   \
    gl_lds16(kgb + (size_t)(t)*4096 + 512,  &Ks[buf][(wid*16+8)*64]); \
    gl_lds16(vgb + (size_t)(t)*64,          &Vs[buf][(wid*16)*64]);   \
    gl_lds16(vgb + (size_t)(t)*64 + 8*2048, &Vs[buf][(wid*16+8)*64]); \
  } while(0)

  STAGE(0, 0);

  bf16x8 b_q[2];   // Q as B-operand: col q = lr, k(e) = ks*32 + 8g + j
  {
    const unsigned short* qp = Qb + ((size_t)bh*2048 + qw + lr)*64;
    b_q[0] = *reinterpret_cast<const bf16x8*>(qp + g*8);
    b_q[1] = *reinterpret_cast<const bf16x8*>(qp + 32 + g*8);
  }
  f32x4 acc[4] = {};   // ctx^T frags: row e = ne*16+4g+j, col q = lr
  float m_run = -3.0e38f, lp = 0.f;
  int cur = 0;
  __syncthreads();     // first tile staged (vmcnt drained by barrier semantics)

  for (int kt = 0; kt < 32; ++kt){
    if (kt < 31) STAGE(cur^1, kt+1);   // issue next-tile DMA; lands before end barrier
    const unsigned short* Kc = Ks[cur];
    const unsigned short* Vc = Vs[cur];
    // QK^T (swapped): A = K rows (k = mk*16+4g+j), B = Q (col q = lr)
    f32x4 st[4] = {};
    __builtin_amdgcn_s_setprio(1);
    #pragma unroll
    for (int mk = 0; mk < 4; ++mk)
      #pragma unroll
      for (int ks = 0; ks < 2; ++ks){
        bf16x8 kf = *reinterpret_cast<const bf16x8*>(
            &Kc[(mk*16 + lr)*64 + (((ks*4 + g) ^ (lr & 7)))*8]);
        st[mk] = __builtin_amdgcn_mfma_f32_16x16x32_bf16(kf, b_q[ks], st[mk], 0,0,0);
      }
    __builtin_amdgcn_s_setprio(0);
    if (!((mbits >> kt) & 1)){
      const int kk0 = kt * 64;
      #pragma unroll
      for (int mk = 0; mk < 4; ++mk)
        #pragma unroll
        for (int j = 0; j < 4; ++j){
          int kg = kk0 + mk*16 + g*4 + j;
          if (mask[mbase + (size_t)(qw + lr)*2048 + kg] == 0) st[mk][j] = -3.0e30f;
        }
    }
    // online softmax (log2 domain, scale folded); lane holds 16 values for q = lr
    float a0 = fmaxf(fmaxf(st[0][0], st[0][1]), fmaxf(st[0][2], st[0][3]));
    float a1 = fmaxf(fmaxf(st[1][0], st[1][1]), fmaxf(st[1][2], st[1][3]));
    float a2 = fmaxf(fmaxf(st[2][0], st[2][1]), fmaxf(st[2][2], st[2][3]));
    float a3 = fmaxf(fmaxf(st[3][0], st[3][1]), fmaxf(st[3][2], st[3][3]));
    float tm = fmaxf(fmaxf(a0, a1), fmaxf(a2, a3));
    tm = fmaxf(tm, __shfl_xor(tm, 16));
    tm = fmaxf(tm, __shfl_xor(tm, 32));
    float tms = tm * SC;
    if (!__all(tms <= m_run + 8.f)){   // defer-max, THR=8 (P bounded by 2^8)
      float mnew = fmaxf(m_run, tms);
      float alpha = exp2f(m_run - mnew);
      lp *= alpha;
      #pragma unroll
      for (int ne = 0; ne < 4; ++ne)
        #pragma unroll
        for (int j = 0; j < 4; ++j) acc[ne][j] *= alpha;
      m_run = mnew;
    }
    // P = exp2(S*SC - m_run); pack bf16 pairs; permlane exchange -> PV B-frags
    unsigned wrd[4][2];
    float psA = 0.f, psB = 0.f;
    #pragma unroll
    for (int mk = 0; mk < 4; ++mk){
      float p0 = exp2f(__builtin_fmaf(st[mk][0], SC, -m_run));
      float p1 = exp2f(__builtin_fmaf(st[mk][1], SC, -m_run));
      float p2 = exp2f(__builtin_fmaf(st[mk][2], SC, -m_run));
      float p3 = exp2f(__builtin_fmaf(st[mk][3], SC, -m_run));
      psA += p0 + p2; psB += p1 + p3;
      wrd[mk][0] = cvt_pk_bf16(p0, p1);
      wrd[mk][1] = cvt_pk_bf16(p2, p3);
    }
    lp += psA + psB;   // per-lane partial; reduced once at the end
    bf16x8 pw[2];
    #pragma unroll
    for (int ks = 0; ks < 2; ++ks){
      unsigned a0w = wrd[2*ks][0], b0w = wrd[2*ks+1][0];
      unsigned a1w = wrd[2*ks][1], b1w = wrd[2*ks+1][1];
      plswap32(a0w, b0w); plswap16(a0w, b0w);
      plswap32(a1w, b1w); plswap16(a1w, b1w);
      u32x4 pk = { a0w, a1w, b0w, b1w };
      pw[ks] = __builtin_bit_cast(bf16x8, pk);
    }
    // PV: ctx^T += Vt * P^T
    __builtin_amdgcn_s_setprio(1);
    #pragma unroll
    for (int ks = 0; ks < 2; ++ks)
      #pragma unroll
      for (int ne = 0; ne < 4; ++ne){
        bf16x8 vf = *reinterpret_cast<const bf16x8*>(
            &Vc[(ne*16 + lr)*64 + (((ks*4 + g) ^ (lr & 7)))*8]);
        acc[ne] = __builtin_amdgcn_mfma_f32_16x16x32_bf16(vf, pw[ks], acc[ne], 0,0,0);
      }
    __builtin_amdgcn_s_setprio(0);
    if (kt < 31){
      __syncthreads();   // drains next-tile DMA + orders buffer reuse
      cur ^= 1;
    }
  }
  #undef STAGE
  float l = lp;
  l += __shfl_xor(l, 16);
  l += __shfl_xor(l, 32);
  float inv = 1.f / l;
  int q = qw + lr;
  #pragma unroll
  for (int ne = 0; ne < 4; ++ne){
    uint2 ow;
    ow.x = cvt_pk_bf16(acc[ne][0]*inv, acc[ne][1]*inv);
    ow.y = cvt_pk_bf16(acc[ne][2]*inv, acc[ne][3]*inv);
    *reinterpret_cast<uint2*>(&ctx[((size_t)b*2048 + q)*512 + h*64 + ne*16 + g*4]) = ow;
  }
}

// ---------- LayerNorm: wave per row of 512 ----------
__global__ __launch_bounds__(256) void k_ln(
    const float* __restrict__ in, const float* __restrict__ gma, const float* __restrict__ bta,
    float* __restrict__ of, unsigned short* __restrict__ ob)
{
  const int lane = threadIdx.x & 63, wid = threadIdx.x >> 6;
  const size_t row = (size_t)blockIdx.x * 4 + wid;
  const float* x = in + row * 512;
  const int e0 = lane * 8;
  float xv[8];
  *reinterpret_cast<float4*>(&xv[0]) = *reinterpret_cast<const float4*>(x + e0);
  *reinterpret_cast<float4*>(&xv[4]) = *reinterpret_cast<const float4*>(x + e0 + 4);
  float s = 0.f, ss = 0.f;
  #pragma unroll
  for (int i = 0; i < 8; ++i){ s += xv[i]; ss += xv[i]*xv[i]; }
  #pragma unroll
  for (int o = 1; o < 64; o <<= 1){ s += __shfl_xor(s, o); ss += __shfl_xor(ss, o); }
  float mu = s * (1.f/512.f);
  float var = ss * (1.f/512.f) - mu*mu;
  float rs = rsqrtf(var + 1e-5f);
  float gv[8], bv[8], y[8];
  *reinterpret_cast<float4*>(&gv[0]) = *reinterpret_cast<const float4*>(gma + e0);
  *reinterpret_cast<float4*>(&gv[4]) = *reinterpret_cast<const float4*>(gma + e0 + 4);
  *reinterpret_cast<float4*>(&bv[0]) = *reinterpret_cast<const float4*>(bta + e0);
  *reinterpret_cast<float4*>(&bv[4]) = *reinterpret_cast<const float4*>(bta + e0 + 4);
  #pragma unroll
  for (int i = 0; i < 8; ++i) y[i] = (xv[i]-mu)*rs*gv[i] + bv[i];
  *reinterpret_cast<float4*>(of + row*512 + e0)     = *reinterpret_cast<float4*>(&y[0]);
  *reinterpret_cast<float4*>(of + row*512 + e0 + 4) = *reinterpret_cast<float4*>(&y[4]);
  if (ob){
    us4 o0 = { f2bf(y[0]), f2bf(y[1]), f2bf(y[2]), f2bf(y[3]) };
    us4 o1 = { f2bf(y[4]), f2bf(y[5]), f2bf(y[6]), f2bf(y[7]) };
    *reinterpret_cast<us4*>(ob + row*512 + e0)     = o0;
    *reinterpret_cast<us4*>(ob + row*512 + e0 + 4) = o1;
  }
}

extern "C" void kernel_launch(void* const* d_in, const int* in_sizes, int n_in,
                              void* d_out, int out_size, void* d_ws, size_t ws_size,
                              hipStream_t stream)
{
  const float* src  = (const float*)d_in[0];
  const int*   mask = (const int*)d_in[1];
  const float* q_w  = (const float*)d_in[2];
  const float* q_b  = (const float*)d_in[3];
  const float* k_w  = (const float*)d_in[4];
  const float* k_b  = (const float*)d_in[5];
  const float* v_w  = (const float*)d_in[6];
  const float* v_b  = (const float*)d_in[7];
  const float* o_w  = (const float*)d_in[8];
  const float* o_b  = (const float*)d_in[9];
  const float* ln1g = (const float*)d_in[10];
  const float* ln1b = (const float*)d_in[11];
  const float* w1   = (const float*)d_in[12];
  const float* b1   = (const float*)d_in[13];
  const float* w2   = (const float*)d_in[14];
  const float* b2   = (const float*)d_in[15];
  const float* ln2g = (const float*)d_in[16];
  const float* ln2b = (const float*)d_in[17];

  char* ws = (char*)d_ws;
  if (ws_size < 81795072) return;
  unsigned short* x_bf  = (unsigned short*)(ws + 0);          // 8.4MB (reused as LN1 bf16 out)
  unsigned short* wtqkv = (unsigned short*)(ws + 8388608);
  float*          bqkv  = (float*)(ws + 9961472);
  unsigned short* wto   = (unsigned short*)(ws + 9967616);
  unsigned short* wt1   = (unsigned short*)(ws + 10491904);
  unsigned short* wt2   = (unsigned short*)(ws + 12589056);
  unsigned short* Qb    = (unsigned short*)(ws + 14686208);
  unsigned short* Kb    = (unsigned short*)(ws + 23074816);
  unsigned short* Vt    = (unsigned short*)(ws + 31463424);
  unsigned short* ctx   = (unsigned short*)(ws + 39852032);
  unsigned short* ffb   = (unsigned short*)(ws + 14686208);   // overlays Q/K/Vt/ctx (dead by FF1)
  float* res = (float*)(ws + 48240640);                        // res1 then res2
  float* xf  = (float*)(ws + 65017856);
  unsigned short* mb16 = (unsigned short*)(ws + 48240640);     // bitmap in res head (dead by gemm<1>)
  const unsigned* mb32 = (const unsigned*)(ws + 48240640);
  float* outf = (float*)d_out;

  k_maskbits<<<dim3(128,2), 256, 0, stream>>>(mask, mb16);
  k_f2b<<<4096, 256, 0, stream>>>(src, x_bf, 1048576);
  k_wtrans_qkv<<<dim3(16,2,24), 256, 0, stream>>>(q_w, k_w, v_w, wtqkv);
  k_bqkv<<<6, 256, 0, stream>>>(q_b, k_b, v_b, bqkv);
  k_wtrans<<<dim3(16,16), 256, 0, stream>>>(o_w, wto, 512, 512);
  k_wtrans<<<dim3(16,64), 256, 0, stream>>>(w1, wt1, 512, 2048);
  k_wtrans<<<dim3(64,16), 256, 0, stream>>>(w2, wt2, 2048, 512);

  k_gemm<0><<<dim3(64,12), 256, 0, stream>>>(x_bf, wtqkv, bqkv, nullptr,
                                             Qb, Kb, Vt, nullptr, 8192, 1536, 512);
  k_attn<<<dim3(32,32), 256, 0, stream>>>(Qb, Kb, Vt, mask, mb32, ctx);
  k_gemm<1><<<dim3(64,4), 256, 0, stream>>>(ctx, wto, o_b, src,
                                            nullptr, nullptr, nullptr, res, 8192, 512, 512);
  k_ln<<<2048, 256, 0, stream>>>(res, ln1g, ln1b, xf, x_bf);
  k_gemm<2><<<dim3(64,16), 256, 0, stream>>>(x_bf, wt1, b1, nullptr,
                                             ffb, nullptr, nullptr, nullptr, 8192, 2048, 512);
  k_gemm<3><<<dim3(64,4), 256, 0, stream>>>(ffb, wt2, b2, xf,
                                            nullptr, nullptr, nullptr, res, 8192, 512, 2048);
  k_ln<<<2048, 256, 0, stream>>>(res, ln2g, ln2b, outf, nullptr);
}

// Round 10
// 221.073 us; speedup vs baseline: 1.3457x; 1.0425x over previous
//
#include <hip/hip_runtime.h>

// TransformerDecoderLayer: B=4,S=2048,D=512,H=8,DK=64,DFF=2048, fp32 in/out.
// R10 = R9 (230us) with attn restructured to 8-wave/512-thread blocks, grid (16,32):
// 8 waves share one K/V tile (halves HBM fetch + staging instrs, doubles waves/CU).
// Per-wave workload identical to R9 (16 q rows, online softmax, in-reg P).
// v_max3-friendly max tree. GEMMs/LN/prep byte-identical to R9.

typedef __bf16 bf16x8 __attribute__((ext_vector_type(8)));
typedef float f32x4 __attribute__((ext_vector_type(4)));
typedef unsigned short us4 __attribute__((ext_vector_type(4)));
typedef unsigned u32x4 __attribute__((ext_vector_type(4)));

__device__ __forceinline__ unsigned short f2bf(float f){
  unsigned u = __builtin_bit_cast(unsigned, f);
  u += 0x7fffu + ((u >> 16) & 1u);   // RNE
  return (unsigned short)(u >> 16);
}

__device__ __forceinline__ unsigned cvt_pk_bf16(float lo, float hi){
  unsigned r;
  asm("v_cvt_pk_bf16_f32 %0, %1, %2" : "=v"(r) : "v"(lo), "v"(hi));
  return r;
}
__device__ __forceinline__ void plswap32(unsigned &a, unsigned &b){
  asm volatile("v_permlane32_swap_b32 %0, %1" : "+v"(a), "+v"(b));
}
__device__ __forceinline__ void plswap16(unsigned &a, unsigned &b){
  asm volatile("v_permlane16_swap_b32 %0, %1" : "+v"(a), "+v"(b));
}

typedef const __attribute__((address_space(1))) void* gas_t;
typedef __attribute__((address_space(3))) void* las_t;
__device__ __forceinline__ void gl_lds16(const void* g, void* l){
  __builtin_amdgcn_global_load_lds((gas_t)g, (las_t)l, 16, 0, 0);
}

// ---------- f32 -> bf16 convert (4 elems/thread) ----------
__global__ void k_f2b(const float* __restrict__ in, unsigned short* __restrict__ out, int n4){
  int i = blockIdx.x * 256 + threadIdx.x;
  if (i < n4){
    float4 v = reinterpret_cast<const float4*>(in)[i];
    us4 o = { f2bf(v.x), f2bf(v.y), f2bf(v.z), f2bf(v.w) };
    reinterpret_cast<us4*>(out)[i] = o;
  }
}

// ---------- weight transpose+convert: in[K][N] f32 -> out[N][K] bf16 ----------
__global__ void k_wtrans(const float* __restrict__ in, unsigned short* __restrict__ out, int K, int N){
  __shared__ float t[32][33];
  int k0 = blockIdx.x*32, n0 = blockIdx.y*32;
  int tx = threadIdx.x & 31, ty = threadIdx.x >> 5;
  #pragma unroll
  for (int r = 0; r < 4; ++r)
    t[ty + 8*r][tx] = in[(size_t)(k0 + ty + 8*r)*N + n0 + tx];
  __syncthreads();
  #pragma unroll
  for (int r = 0; r < 4; ++r)
    out[(size_t)(n0 + ty + 8*r)*K + k0 + tx] = f2bf(t[tx][ty + 8*r]);
}

// qkv weights [H,512,64] (x3) -> Wt_qkv[1536][512], row n = sel*512 + h*64 + e
__global__ void k_wtrans_qkv(const float* __restrict__ qw, const float* __restrict__ kw,
                             const float* __restrict__ vw, unsigned short* __restrict__ out){
  __shared__ float t[32][33];
  int z = blockIdx.z, sel = z >> 3, h = z & 7;
  const float* in = (sel==0 ? qw : (sel==1 ? kw : vw)) + (size_t)h*512*64;
  unsigned short* o = out + ((size_t)(sel*512 + h*64)) * 512;
  int k0 = blockIdx.x*32, n0 = blockIdx.y*32;
  int tx = threadIdx.x & 31, ty = threadIdx.x >> 5;
  #pragma unroll
  for (int r = 0; r < 4; ++r)
    t[ty + 8*r][tx] = in[(size_t)(k0 + ty + 8*r)*64 + n0 + tx];
  __syncthreads();
  #pragma unroll
  for (int r = 0; r < 4; ++r)
    o[(size_t)(n0 + ty + 8*r)*512 + k0 + tx] = f2bf(t[tx][ty + 8*r]);
}

__global__ void k_bqkv(const float* __restrict__ qb, const float* __restrict__ kb,
                       const float* __restrict__ vb, float* __restrict__ out){
  int n = blockIdx.x*256 + threadIdx.x;
  if (n < 1536){ int sel = n >> 9, r = n & 511;
    out[n] = (sel==0 ? qb : (sel==1 ? kb : vb))[r]; }
}

// ---------- mask tile bitmap: out16[b*32+qt][half] bit i = tile(qt, half*16+i) all-ones ----------
__global__ __launch_bounds__(256) void k_maskbits(const int* __restrict__ mask, unsigned short* __restrict__ out){
  const int tid = threadIdx.x;
  const int bq = blockIdx.x;            // b*32 + qt
  const int half = blockIdx.y;          // kt halves
  const int b = bq >> 5, qt = bq & 31;
  const int* base = mask + (size_t)b*2048*2048 + (size_t)(qt*64 + (tid>>4)*4)*2048 + (tid&15)*4;
  unsigned bits = 0;
  for (int i = 0; i < 16; ++i){
    const int* p = base + (half*16 + i)*64;
    int ok = 1;
    #pragma unroll
    for (int r = 0; r < 4; ++r){
      int4 v = *reinterpret_cast<const int4*>(p + (size_t)r*2048);
      ok &= (v.x!=0)&(v.y!=0)&(v.z!=0)&(v.w!=0);
    }
    bits |= (unsigned)ok << i;
  }
  #pragma unroll
  for (int o = 1; o < 64; o <<= 1) bits &= __shfl_xor(bits, o);
  __shared__ unsigned red[4];
  if ((tid & 63) == 0) red[tid >> 6] = bits;
  __syncthreads();
  if (tid == 0) out[bq*2 + half] = (unsigned short)(red[0]&red[1]&red[2]&red[3]);
}

// ---------- GEMM (R2-identical): C[M,N] = A[M,K] * Bt[N,K]^T + bias, fused epilogues ----------
// MODE 0: QKV scatter; 1: +resid f32 (O-proj); 2: bf16 relu (FF1); 3: +resid f32 (FF2)
template<int MODE>
__global__ __launch_bounds__(256, 3) void k_gemm(
    const unsigned short* __restrict__ A, const unsigned short* __restrict__ Bt,
    const float* __restrict__ bias, const float* __restrict__ resid,
    unsigned short* __restrict__ ob0, unsigned short* __restrict__ ob1, unsigned short* __restrict__ ob2,
    float* __restrict__ of, int M, int N, int K)
{
  __shared__ unsigned short As[128*32];   // linear [128][32]
  __shared__ unsigned short Bs[128*32];
  const int tid = threadIdx.x, lane = tid & 63, wid = tid >> 6;
  const int g = lane >> 4, lr = lane & 15;
  const int rowBase = blockIdx.x * 128, colBase = blockIdx.y * 128;
  const int wr = (wid >> 1) * 64, wc = (wid & 1) * 64;
  const int srow = wid*32 + (lane >> 2);
  const int gcol = ((lane & 3) ^ ((lane >> 3) & 3)) * 8;   // shorts
  const int rchunk = (g ^ ((lr >> 1) & 3)) * 8;
  unsigned short* lA = &As[wid*1024];
  unsigned short* lB = &Bs[wid*1024];
  const unsigned short* pA = A + (size_t)(rowBase + srow)*K + gcol;
  const unsigned short* pB = Bt + (size_t)(colBase + srow)*K + gcol;
  f32x4 acc[4][4] = {};
  for (int k0 = 0; k0 < K; k0 += 32){
    __syncthreads();
    gl_lds16(pA + k0, lA);
    gl_lds16(pA + (size_t)16*K + k0, lA + 512);
    gl_lds16(pB + k0, lB);
    gl_lds16(pB + (size_t)16*K + k0, lB + 512);
    __syncthreads();
    bf16x8 af[4], bfr[4];
    #pragma unroll
    for (int mi = 0; mi < 4; ++mi) af[mi]  = *reinterpret_cast<const bf16x8*>(&As[(wr + mi*16 + lr)*32 + rchunk]);
    #pragma unroll
    for (int ni = 0; ni < 4; ++ni) bfr[ni] = *reinterpret_cast<const bf16x8*>(&Bs[(wc + ni*16 + lr)*32 + rchunk]);
    #pragma unroll
    for (int mi = 0; mi < 4; ++mi)
      #pragma unroll
      for (int ni = 0; ni < 4; ++ni)
        acc[mi][ni] = __builtin_amdgcn_mfma_f32_16x16x32_bf16(af[mi], bfr[ni], acc[mi][ni], 0, 0, 0);
  }
  float bv[4];
  #pragma unroll
  for (int ni = 0; ni < 4; ++ni) bv[ni] = bias[colBase + wc + ni*16 + lr];
  #pragma unroll
  for (int mi = 0; mi < 4; ++mi){
    #pragma unroll
    for (int ni = 0; ni < 4; ++ni){
      #pragma unroll
      for (int j = 0; j < 4; ++j){
        int m = rowBase + wr + mi*16 + g*4 + j;
        int n = colBase + wc + ni*16 + lr;
        float v = acc[mi][ni][j] + bv[ni];
        if constexpr (MODE == 0){
          int b = m >> 11, s = m & 2047;
          int sel = n >> 9, rr = n & 511, h = rr >> 6, e = rr & 63;
          size_t bh = (size_t)(b*8 + h);
          if (sel == 0)      ob0[(bh*2048 + s)*64 + e] = f2bf(v);
          else if (sel == 1) ob1[(bh*2048 + s)*64 + e] = f2bf(v);
          else               ob2[(bh*64 + e)*2048 + s] = f2bf(v);   // V transposed
        } else if constexpr (MODE == 1 || MODE == 3){
          of[(size_t)m*N + n] = v + resid[(size_t)m*N + n];
        } else {
          ob0[(size_t)m*N + n] = f2bf(v > 0.f ? v : 0.f);
        }
      }
    }
  }
}

// ---------- flash attention: swapped QK^T, 16 q/wave, 8 waves/block, grid (16,32) ----------
// 8 waves share one 64x64 K/V tile (gl_lds chunk-XOR, 2-buf, 1 barrier/tile);
// online softmax (log2, defer-max), in-register P via cvt_pk+permlane, setprio.
__global__ __launch_bounds__(512) void k_attn(
    const unsigned short* __restrict__ Qb, const unsigned short* __restrict__ Kb,
    const unsigned short* __restrict__ Vt, const int* __restrict__ mask,
    const unsigned* __restrict__ mbits_p, unsigned short* __restrict__ ctx)
{
  __shared__ unsigned short Ks[2][4096];   // [64 rows][8 chunks of 8 shorts], chunk-XOR
  __shared__ unsigned short Vs[2][4096];
  const int tid = threadIdx.x, lane = tid & 63, wid = tid >> 6;   // wid 0..7
  const int g = lane >> 4, lr = lane & 15;
  const int qt = blockIdx.x, bh = blockIdx.y;
  const int b = bh >> 3, h = bh & 7;
  const int qw = qt * 128 + wid * 16;
  const unsigned mbits = mbits_p[b*32 + qt*2] & mbits_p[b*32 + qt*2 + 1];
  const size_t mbase = (size_t)b * 2048 * 2048;
  const float SC = 0.18033688f;   // log2(e)/sqrt(64)

  // staging: wave wid covers rows [wid*8, wid*8+8) of K and V (1 gl_lds each).
  // lane covers LDS slot (row8 = lane>>3, chunk = lane&7); source chunk pre-XOR'd
  // so LDS[r][c] = G[r][c^(r&7)]  (row&7 == row8 since wid*8 is 8-aligned).
  const int srow8 = lane >> 3;
  const int schunk = (lane & 7) ^ (srow8 & 7);
  const unsigned short* kgb = Kb + (size_t)bh*2048*64 + ((size_t)(wid*8) + srow8)*64 + schunk*8;
  const unsigned short* vgb = Vt + (size_t)bh*64*2048 + ((size_t)(wid*8) + srow8)*2048 + schunk*8;

  #define STAGE(buf, t) do { \
    gl_lds16(kgb + (size_t)(t)*4096, &Ks[buf][(wid*8)*64]); \
    gl_lds16(vgb + (size_t)(t)*64,   &Vs[buf][(wid*8)*64]); \
  } while(0)

  STAGE(0, 0);

  bf16x8 b_q[2];   // Q as B-operand: col q = lr, k(e) = ks*32 + 8g + j
  {
    const unsigned short* qp = Qb + ((size_t)bh*2048 + qw + lr)*64;
    b_q[0] = *reinterpret_cast<const bf16x8*>(qp + g*8);
    b_q[1] = *reinterpret_cast<const bf16x8*>(qp + 32 + g*8);
  }
  f32x4 acc[4] = {};   // ctx^T frags: row e = ne*16+4g+j, col q = lr
  float m_run = -3.0e38f, lp = 0.f;
  int cur = 0;
  __syncthreads();     // first tile staged (vmcnt drained by barrier semantics)

  for (int kt = 0; kt < 32; ++kt){
    if (kt < 31) STAGE(cur^1, kt+1);   // issue next-tile DMA; lands before end barrier
    const unsigned short* Kc = Ks[cur];
    const unsigned short* Vc = Vs[cur];
    // QK^T (swapped): A = K rows (k = mk*16+4g+j), B = Q (col q = lr)
    f32x4 st[4] = {};
    __builtin_amdgcn_s_setprio(1);
    #pragma unroll
    for (int mk = 0; mk < 4; ++mk)
      #pragma unroll
      for (int ks = 0; ks < 2; ++ks){
        bf16x8 kf = *reinterpret_cast<const bf16x8*>(
            &Kc[(mk*16 + lr)*64 + (((ks*4 + g) ^ (lr & 7)))*8]);
        st[mk] = __builtin_amdgcn_mfma_f32_16x16x32_bf16(kf, b_q[ks], st[mk], 0,0,0);
      }
    __builtin_amdgcn_s_setprio(0);
    if (!((mbits >> kt) & 1)){
      const int kk0 = kt * 64;
      #pragma unroll
      for (int mk = 0; mk < 4; ++mk)
        #pragma unroll
        for (int j = 0; j < 4; ++j){
          int kg = kk0 + mk*16 + g*4 + j;
          if (mask[mbase + (size_t)(qw + lr)*2048 + kg] == 0) st[mk][j] = -3.0e30f;
        }
    }
    // online softmax (log2 domain); v_max3-friendly reduction tree (T17)
    float x0 = fmaxf(fmaxf(st[0][0], st[0][1]), st[0][2]);
    float x1 = fmaxf(fmaxf(st[0][3], st[1][0]), st[1][1]);
    float x2 = fmaxf(fmaxf(st[1][2], st[1][3]), st[2][0]);
    float x3 = fmaxf(fmaxf(st[2][1], st[2][2]), st[2][3]);
    float x4 = fmaxf(fmaxf(st[3][0], st[3][1]), st[3][2]);
    float tm = fmaxf(fmaxf(fmaxf(x0, x1), x2), fmaxf(fmaxf(x3, x4), st[3][3]));
    tm = fmaxf(tm, __shfl_xor(tm, 16));
    tm = fmaxf(tm, __shfl_xor(tm, 32));
    float tms = tm * SC;
    if (!__all(tms <= m_run + 8.f)){   // defer-max, THR=8 (P bounded by 2^8)
      float mnew = fmaxf(m_run, tms);
      float alpha = exp2f(m_run - mnew);
      lp *= alpha;
      #pragma unroll
      for (int ne = 0; ne < 4; ++ne)
        #pragma unroll
        for (int j = 0; j < 4; ++j) acc[ne][j] *= alpha;
      m_run = mnew;
    }
    // P = exp2(S*SC - m_run); pack bf16 pairs; permlane exchange -> PV B-frags
    unsigned wrd[4][2];
    float psA = 0.f, psB = 0.f;
    #pragma unroll
    for (int mk = 0; mk < 4; ++mk){
      float p0 = exp2f(__builtin_fmaf(st[mk][0], SC, -m_run));
      float p1 = exp2f(__builtin_fmaf(st[mk][1], SC, -m_run));
      float p2 = exp2f(__builtin_fmaf(st[mk][2], SC, -m_run));
      float p3 = exp2f(__builtin_fmaf(st[mk][3], SC, -m_run));
      psA += p0 + p2; psB += p1 + p3;
      wrd[mk][0] = cvt_pk_bf16(p0, p1);
      wrd[mk][1] = cvt_pk_bf16(p2, p3);
    }
    lp += psA + psB;   // per-lane partial; reduced once at the end
    bf16x8 pw[2];
    #pragma unroll
    for (int ks = 0; ks < 2; ++ks){
      unsigned a0w = wrd[2*ks][0], b0w = wrd[2*ks+1][0];
      unsigned a1w = wrd[2*ks][1], b1w = wrd[2*ks+1][1];
      plswap32(a0w, b0w); plswap16(a0w, b0w);
      plswap32(a1w, b1w); plswap16(a1w, b1w);
      u32x4 pk = { a0w, a1w, b0w, b1w };
      pw[ks] = __builtin_bit_cast(bf16x8, pk);
    }
    // PV: ctx^T += Vt * P^T
    __builtin_amdgcn_s_setprio(1);
    #pragma unroll
    for (int ks = 0; ks < 2; ++ks)
      #pragma unroll
      for (int ne = 0; ne < 4; ++ne){
        bf16x8 vf = *reinterpret_cast<const bf16x8*>(
            &Vc[(ne*16 + lr)*64 + (((ks*4 + g) ^ (lr & 7)))*8]);
        acc[ne] = __builtin_amdgcn_mfma_f32_16x16x32_bf16(vf, pw[ks], acc[ne], 0,0,0);
      }
    __builtin_amdgcn_s_setprio(0);
    if (kt < 31){
      __syncthreads();   // drains next-tile DMA + orders buffer reuse
      cur ^= 1;
    }
  }
  #undef STAGE
  float l = lp;
  l += __shfl_xor(l, 16);
  l += __shfl_xor(l, 32);
  float inv = 1.f / l;
  int q = qw + lr;
  #pragma unroll
  for (int ne = 0; ne < 4; ++ne){
    uint2 ow;
    ow.x = cvt_pk_bf16(acc[ne][0]*inv, acc[ne][1]*inv);
    ow.y = cvt_pk_bf16(acc[ne][2]*inv, acc[ne][3]*inv);
    *reinterpret_cast<uint2*>(&ctx[((size_t)b*2048 + q)*512 + h*64 + ne*16 + g*4]) = ow;
  }
}

// ---------- LayerNorm: wave per row of 512 ----------
__global__ __launch_bounds__(256) void k_ln(
    const float* __restrict__ in, const float* __restrict__ gma, const float* __restrict__ bta,
    float* __restrict__ of, unsigned short* __restrict__ ob)
{
  const int lane = threadIdx.x & 63, wid = threadIdx.x >> 6;
  const size_t row = (size_t)blockIdx.x * 4 + wid;
  const float* x = in + row * 512;
  const int e0 = lane * 8;
  float xv[8];
  *reinterpret_cast<float4*>(&xv[0]) = *reinterpret_cast<const float4*>(x + e0);
  *reinterpret_cast<float4*>(&xv[4]) = *reinterpret_cast<const float4*>(x + e0 + 4);
  float s = 0.f, ss = 0.f;
  #pragma unroll
  for (int i = 0; i < 8; ++i){ s += xv[i]; ss += xv[i]*xv[i]; }
  #pragma unroll
  for (int o = 1; o < 64; o <<= 1){ s += __shfl_xor(s, o); ss += __shfl_xor(ss, o); }
  float mu = s * (1.f/512.f);
  float var = ss * (1.f/512.f) - mu*mu;
  float rs = rsqrtf(var + 1e-5f);
  float gv[8], bv[8], y[8];
  *reinterpret_cast<float4*>(&gv[0]) = *reinterpret_cast<const float4*>(gma + e0);
  *reinterpret_cast<float4*>(&gv[4]) = *reinterpret_cast<const float4*>(gma + e0 + 4);
  *reinterpret_cast<float4*>(&bv[0]) = *reinterpret_cast<const float4*>(bta + e0);
  *reinterpret_cast<float4*>(&bv[4]) = *reinterpret_cast<const float4*>(bta + e0 + 4);
  #pragma unroll
  for (int i = 0; i < 8; ++i) y[i] = (xv[i]-mu)*rs*gv[i] + bv[i];
  *reinterpret_cast<float4*>(of + row*512 + e0)     = *reinterpret_cast<float4*>(&y[0]);
  *reinterpret_cast<float4*>(of + row*512 + e0 + 4) = *reinterpret_cast<float4*>(&y[4]);
  if (ob){
    us4 o0 = { f2bf(y[0]), f2bf(y[1]), f2bf(y[2]), f2bf(y[3]) };
    us4 o1 = { f2bf(y[4]), f2bf(y[5]), f2bf(y[6]), f2bf(y[7]) };
    *reinterpret_cast<us4*>(ob + row*512 + e0)     = o0;
    *reinterpret_cast<us4*>(ob + row*512 + e0 + 4) = o1;
  }
}

extern "C" void kernel_launch(void* const* d_in, const int* in_sizes, int n_in,
                              void* d_out, int out_size, void* d_ws, size_t ws_size,
                              hipStream_t stream)
{
  const float* src  = (const float*)d_in[0];
  const int*   mask = (const int*)d_in[1];
  const float* q_w  = (const float*)d_in[2];
  const float* q_b  = (const float*)d_in[3];
  const float* k_w  = (const float*)d_in[4];
  const float* k_b  = (const float*)d_in[5];
  const float* v_w  = (const float*)d_in[6];
  const float* v_b  = (const float*)d_in[7];
  const float* o_w  = (const float*)d_in[8];
  const float* o_b  = (const float*)d_in[9];
  const float* ln1g = (const float*)d_in[10];
  const float* ln1b = (const float*)d_in[11];
  const float* w1   = (const float*)d_in[12];
  const float* b1   = (const float*)d_in[13];
  const float* w2   = (const float*)d_in[14];
  const float* b2   = (const float*)d_in[15];
  const float* ln2g = (const float*)d_in[16];
  const float* ln2b = (const float*)d_in[17];

  char* ws = (char*)d_ws;
  if (ws_size < 81795072) return;
  unsigned short* x_bf  = (unsigned short*)(ws + 0);          // 8.4MB (reused as LN1 bf16 out)
  unsigned short* wtqkv = (unsigned short*)(ws + 8388608);
  float*          bqkv  = (float*)(ws + 9961472);
  unsigned short* wto   = (unsigned short*)(ws + 9967616);
  unsigned short* wt1   = (unsigned short*)(ws + 10491904);
  unsigned short* wt2   = (unsigned short*)(ws + 12589056);
  unsigned short* Qb    = (unsigned short*)(ws + 14686208);
  unsigned short* Kb    = (unsigned short*)(ws + 23074816);
  unsigned short* Vt    = (unsigned short*)(ws + 31463424);
  unsigned short* ctx   = (unsigned short*)(ws + 39852032);
  unsigned short* ffb   = (unsigned short*)(ws + 14686208);   // overlays Q/K/Vt/ctx (dead by FF1)
  float* res = (float*)(ws + 48240640);                        // res1 then res2
  float* xf  = (float*)(ws + 65017856);
  unsigned short* mb16 = (unsigned short*)(ws + 48240640);     // bitmap in res head (dead by gemm<1>)
  const unsigned* mb32 = (const unsigned*)(ws + 48240640);
  float* outf = (float*)d_out;

  k_maskbits<<<dim3(128,2), 256, 0, stream>>>(mask, mb16);
  k_f2b<<<4096, 256, 0, stream>>>(src, x_bf, 1048576);
  k_wtrans_qkv<<<dim3(16,2,24), 256, 0, stream>>>(q_w, k_w, v_w, wtqkv);
  k_bqkv<<<6, 256, 0, stream>>>(q_b, k_b, v_b, bqkv);
  k_wtrans<<<dim3(16,16), 256, 0, stream>>>(o_w, wto, 512, 512);
  k_wtrans<<<dim3(16,64), 256, 0, stream>>>(w1, wt1, 512, 2048);
  k_wtrans<<<dim3(64,16), 256, 0, stream>>>(w2, wt2, 2048, 512);

  k_gemm<0><<<dim3(64,12), 256, 0, stream>>>(x_bf, wtqkv, bqkv, nullptr,
                                             Qb, Kb, Vt, nullptr, 8192, 1536, 512);
  k_attn<<<dim3(16,32), 512, 0, stream>>>(Qb, Kb, Vt, mask, mb32, ctx);
  k_gemm<1><<<dim3(64,4), 256, 0, stream>>>(ctx, wto, o_b, src,
                                            nullptr, nullptr, nullptr, res, 8192, 512, 512);
  k_ln<<<2048, 256, 0, stream>>>(res, ln1g, ln1b, xf, x_bf);
  k_gemm<2><<<dim3(64,16), 256, 0, stream>>>(x_bf, wt1, b1, nullptr,
                                             ffb, nullptr, nullptr, nullptr, 8192, 2048, 512);
  k_gemm<3><<<dim3(64,4), 256, 0, stream>>>(ffb, wt2, b2, xf,
                                            nullptr, nullptr, nullptr, res, 8192, 512, 2048);
  k_ln<<<2048, 256, 0, stream>>>(res, ln2g, ln2b, outf, nullptr);
}

// Round 11
// 206.711 us; speedup vs baseline: 1.4392x; 1.0695x over previous
//
#include <hip/hip_runtime.h>

// TransformerDecoderLayer: B=4,S=2048,D=512,H=8,DK=64,DFF=2048, fp32 in/out.
// R11 = R10 (221us) with:
//  (1) mega-prep: maskbits+f2b+wtrans_qkv+bqkv+3xwtrans fused into ONE kernel
//      (flat-id dispatch, maskbits blocks first) -> 14 launches down to 8.
//  (2) attn grid transposed to (32,16): bh = blockIdx.x -> same-bh blocks land
//      on one XCD (round-robin) -> K/V re-reads become L2 hits.
// attn body / GEMMs / LN byte-identical to R10.

typedef __bf16 bf16x8 __attribute__((ext_vector_type(8)));
typedef float f32x4 __attribute__((ext_vector_type(4)));
typedef unsigned short us4 __attribute__((ext_vector_type(4)));
typedef unsigned u32x4 __attribute__((ext_vector_type(4)));

__device__ __forceinline__ unsigned short f2bf(float f){
  unsigned u = __builtin_bit_cast(unsigned, f);
  u += 0x7fffu + ((u >> 16) & 1u);   // RNE
  return (unsigned short)(u >> 16);
}

__device__ __forceinline__ unsigned cvt_pk_bf16(float lo, float hi){
  unsigned r;
  asm("v_cvt_pk_bf16_f32 %0, %1, %2" : "=v"(r) : "v"(lo), "v"(hi));
  return r;
}
__device__ __forceinline__ void plswap32(unsigned &a, unsigned &b){
  asm volatile("v_permlane32_swap_b32 %0, %1" : "+v"(a), "+v"(b));
}
__device__ __forceinline__ void plswap16(unsigned &a, unsigned &b){
  asm volatile("v_permlane16_swap_b32 %0, %1" : "+v"(a), "+v"(b));
}

typedef const __attribute__((address_space(1))) void* gas_t;
typedef __attribute__((address_space(3))) void* las_t;
__device__ __forceinline__ void gl_lds16(const void* g, void* l){
  __builtin_amdgcn_global_load_lds((gas_t)g, (las_t)l, 16, 0, 0);
}

// ---------- mega-prep: all input conversions in one kernel ----------
// flat grid 7430 x 256thr:
//   [0,256)      maskbits  (bq = id&127, half = id>>7)
//   [256,4352)   f2b       (4096 blocks)
//   [4352,5120)  wtrans_qkv(768: z=id/32, x=rem&15, y=rem>>4)
//   [5120,5126)  bqkv      (6)
//   [5126,5382)  wtrans o_w  (256: x=id&15, y=id>>4)   K=512,N=512
//   [5382,6406)  wtrans w1   (1024: x=id&15, y=id>>4)  K=512,N=2048
//   [6406,7430)  wtrans w2   (1024: x=id&63, y=id>>6)  K=2048,N=512
struct PrepSh { float t[32][33]; unsigned red[4]; };

__device__ __forceinline__ void wtrans_body(const float* __restrict__ in,
    unsigned short* __restrict__ out, int K, int N, int k0, int n0, int tid,
    float (*t)[33]){
  int tx = tid & 31, ty = tid >> 5;
  #pragma unroll
  for (int r = 0; r < 4; ++r)
    t[ty + 8*r][tx] = in[(size_t)(k0 + ty + 8*r)*N + n0 + tx];
  __syncthreads();
  #pragma unroll
  for (int r = 0; r < 4; ++r)
    out[(size_t)(n0 + ty + 8*r)*K + k0 + tx] = f2bf(t[tx][ty + 8*r]);
}

__global__ __launch_bounds__(256) void k_prep(
    const int* __restrict__ mask, const float* __restrict__ src,
    const float* __restrict__ qw, const float* __restrict__ kw, const float* __restrict__ vw,
    const float* __restrict__ qb, const float* __restrict__ kb, const float* __restrict__ vb,
    const float* __restrict__ ow, const float* __restrict__ w1, const float* __restrict__ w2,
    unsigned short* __restrict__ mb16, unsigned short* __restrict__ x_bf,
    unsigned short* __restrict__ wtqkv, float* __restrict__ bqkv,
    unsigned short* __restrict__ wto, unsigned short* __restrict__ wt1,
    unsigned short* __restrict__ wt2)
{
  __shared__ PrepSh sh;
  const int tid = threadIdx.x;
  int id = blockIdx.x;
  if (id < 256){
    // ---- maskbits ----
    const int bq = id & 127, half = id >> 7;
    const int b = bq >> 5, qt = bq & 31;
    const int* base = mask + (size_t)b*2048*2048 + (size_t)(qt*64 + (tid>>4)*4)*2048 + (tid&15)*4;
    unsigned bits = 0;
    for (int i = 0; i < 16; ++i){
      const int* p = base + (half*16 + i)*64;
      int ok = 1;
      #pragma unroll
      for (int r = 0; r < 4; ++r){
        int4 v = *reinterpret_cast<const int4*>(p + (size_t)r*2048);
        ok &= (v.x!=0)&(v.y!=0)&(v.z!=0)&(v.w!=0);
      }
      bits |= (unsigned)ok << i;
    }
    #pragma unroll
    for (int o = 1; o < 64; o <<= 1) bits &= __shfl_xor(bits, o);
    if ((tid & 63) == 0) sh.red[tid >> 6] = bits;
    __syncthreads();
    if (tid == 0) mb16[bq*2 + half] = (unsigned short)(sh.red[0]&sh.red[1]&sh.red[2]&sh.red[3]);
    return;
  }
  id -= 256;
  if (id < 4096){
    // ---- f2b (src -> x_bf), 4 f32/thread ----
    int i = id * 256 + tid;
    float4 v = reinterpret_cast<const float4*>(src)[i];
    us4 o = { f2bf(v.x), f2bf(v.y), f2bf(v.z), f2bf(v.w) };
    reinterpret_cast<us4*>(x_bf)[i] = o;
    return;
  }
  id -= 4096;
  if (id < 768){
    // ---- wtrans_qkv ----
    int z = id / 32, rem = id % 32, x = rem & 15, y = rem >> 4;
    int sel = z >> 3, h = z & 7;
    const float* in = (sel==0 ? qw : (sel==1 ? kw : vw)) + (size_t)h*512*64;
    unsigned short* o = wtqkv + ((size_t)(sel*512 + h*64)) * 512;
    wtrans_body(in, o, 512, 64, x*32, y*32, tid, sh.t);
    return;
  }
  id -= 768;
  if (id < 6){
    int n = id*256 + tid;
    if (n < 1536){ int sel = n >> 9, r = n & 511;
      bqkv[n] = (sel==0 ? qb : (sel==1 ? kb : vb))[r]; }
    return;
  }
  id -= 6;
  if (id < 256){
    wtrans_body(ow, wto, 512, 512, (id & 15)*32, (id >> 4)*32, tid, sh.t);
    return;
  }
  id -= 256;
  if (id < 1024){
    wtrans_body(w1, wt1, 512, 2048, (id & 15)*32, (id >> 4)*32, tid, sh.t);
    return;
  }
  id -= 1024;
  wtrans_body(w2, wt2, 2048, 512, (id & 63)*32, (id >> 6)*32, tid, sh.t);
}

// ---------- GEMM (R2-identical): C[M,N] = A[M,K] * Bt[N,K]^T + bias, fused epilogues ----------
// MODE 0: QKV scatter; 1: +resid f32 (O-proj); 2: bf16 relu (FF1); 3: +resid f32 (FF2)
template<int MODE>
__global__ __launch_bounds__(256, 3) void k_gemm(
    const unsigned short* __restrict__ A, const unsigned short* __restrict__ Bt,
    const float* __restrict__ bias, const float* __restrict__ resid,
    unsigned short* __restrict__ ob0, unsigned short* __restrict__ ob1, unsigned short* __restrict__ ob2,
    float* __restrict__ of, int M, int N, int K)
{
  __shared__ unsigned short As[128*32];   // linear [128][32]
  __shared__ unsigned short Bs[128*32];
  const int tid = threadIdx.x, lane = tid & 63, wid = tid >> 6;
  const int g = lane >> 4, lr = lane & 15;
  const int rowBase = blockIdx.x * 128, colBase = blockIdx.y * 128;
  const int wr = (wid >> 1) * 64, wc = (wid & 1) * 64;
  const int srow = wid*32 + (lane >> 2);
  const int gcol = ((lane & 3) ^ ((lane >> 3) & 3)) * 8;   // shorts
  const int rchunk = (g ^ ((lr >> 1) & 3)) * 8;
  unsigned short* lA = &As[wid*1024];
  unsigned short* lB = &Bs[wid*1024];
  const unsigned short* pA = A + (size_t)(rowBase + srow)*K + gcol;
  const unsigned short* pB = Bt + (size_t)(colBase + srow)*K + gcol;
  f32x4 acc[4][4] = {};
  for (int k0 = 0; k0 < K; k0 += 32){
    __syncthreads();
    gl_lds16(pA + k0, lA);
    gl_lds16(pA + (size_t)16*K + k0, lA + 512);
    gl_lds16(pB + k0, lB);
    gl_lds16(pB + (size_t)16*K + k0, lB + 512);
    __syncthreads();
    bf16x8 af[4], bfr[4];
    #pragma unroll
    for (int mi = 0; mi < 4; ++mi) af[mi]  = *reinterpret_cast<const bf16x8*>(&As[(wr + mi*16 + lr)*32 + rchunk]);
    #pragma unroll
    for (int ni = 0; ni < 4; ++ni) bfr[ni] = *reinterpret_cast<const bf16x8*>(&Bs[(wc + ni*16 + lr)*32 + rchunk]);
    #pragma unroll
    for (int mi = 0; mi < 4; ++mi)
      #pragma unroll
      for (int ni = 0; ni < 4; ++ni)
        acc[mi][ni] = __builtin_amdgcn_mfma_f32_16x16x32_bf16(af[mi], bfr[ni], acc[mi][ni], 0, 0, 0);
  }
  float bv[4];
  #pragma unroll
  for (int ni = 0; ni < 4; ++ni) bv[ni] = bias[colBase + wc + ni*16 + lr];
  #pragma unroll
  for (int mi = 0; mi < 4; ++mi){
    #pragma unroll
    for (int ni = 0; ni < 4; ++ni){
      #pragma unroll
      for (int j = 0; j < 4; ++j){
        int m = rowBase + wr + mi*16 + g*4 + j;
        int n = colBase + wc + ni*16 + lr;
        float v = acc[mi][ni][j] + bv[ni];
        if constexpr (MODE == 0){
          int b = m >> 11, s = m & 2047;
          int sel = n >> 9, rr = n & 511, h = rr >> 6, e = rr & 63;
          size_t bh = (size_t)(b*8 + h);
          if (sel == 0)      ob0[(bh*2048 + s)*64 + e] = f2bf(v);
          else if (sel == 1) ob1[(bh*2048 + s)*64 + e] = f2bf(v);
          else               ob2[(bh*64 + e)*2048 + s] = f2bf(v);   // V transposed
        } else if constexpr (MODE == 1 || MODE == 3){
          of[(size_t)m*N + n] = v + resid[(size_t)m*N + n];
        } else {
          ob0[(size_t)m*N + n] = f2bf(v > 0.f ? v : 0.f);
        }
      }
    }
  }
}

// ---------- flash attention: swapped QK^T, 16 q/wave, 8 waves/block, grid (32,16) ----------
// bh = blockIdx.x -> same-bh blocks round-robin onto ONE XCD (K/V L2-resident).
// 8 waves share one 64x64 K/V tile (gl_lds chunk-XOR, 2-buf, 1 barrier/tile);
// online softmax (log2, defer-max), in-register P via cvt_pk+permlane, setprio.
__global__ __launch_bounds__(512) void k_attn(
    const unsigned short* __restrict__ Qb, const unsigned short* __restrict__ Kb,
    const unsigned short* __restrict__ Vt, const int* __restrict__ mask,
    const unsigned* __restrict__ mbits_p, unsigned short* __restrict__ ctx)
{
  __shared__ unsigned short Ks[2][4096];   // [64 rows][8 chunks of 8 shorts], chunk-XOR
  __shared__ unsigned short Vs[2][4096];
  const int tid = threadIdx.x, lane = tid & 63, wid = tid >> 6;   // wid 0..7
  const int g = lane >> 4, lr = lane & 15;
  const int qt = blockIdx.y, bh = blockIdx.x;   // transposed grid: bh fastest
  const int b = bh >> 3, h = bh & 7;
  const int qw = qt * 128 + wid * 16;
  const unsigned mbits = mbits_p[b*32 + qt*2] & mbits_p[b*32 + qt*2 + 1];
  const size_t mbase = (size_t)b * 2048 * 2048;
  const float SC = 0.18033688f;   // log2(e)/sqrt(64)

  // staging: wave wid covers rows [wid*8, wid*8+8) of K and V (1 gl_lds each).
  const int srow8 = lane >> 3;
  const int schunk = (lane & 7) ^ (srow8 & 7);
  const unsigned short* kgb = Kb + (size_t)bh*2048*64 + ((size_t)(wid*8) + srow8)*64 + schunk*8;
  const unsigned short* vgb = Vt + (size_t)bh*64*2048 + ((size_t)(wid*8) + srow8)*2048 + schunk*8;

  #define STAGE(buf, t) do { \
    gl_lds16(kgb + (size_t)(t)*4096, &Ks[buf][(wid*8)*64]); \
    gl_lds16(vgb + (size_t)(t)*64,   &Vs[buf][(wid*8)*64]); \
  } while(0)

  STAGE(0, 0);

  bf16x8 b_q[2];   // Q as B-operand: col q = lr, k(e) = ks*32 + 8g + j
  {
    const unsigned short* qp = Qb + ((size_t)bh*2048 + qw + lr)*64;
    b_q[0] = *reinterpret_cast<const bf16x8*>(qp + g*8);
    b_q[1] = *reinterpret_cast<const bf16x8*>(qp + 32 + g*8);
  }
  f32x4 acc[4] = {};   // ctx^T frags: row e = ne*16+4g+j, col q = lr
  float m_run = -3.0e38f, lp = 0.f;
  int cur = 0;
  __syncthreads();     // first tile staged (vmcnt drained by barrier semantics)

  for (int kt = 0; kt < 32; ++kt){
    if (kt < 31) STAGE(cur^1, kt+1);   // issue next-tile DMA; lands before end barrier
    const unsigned short* Kc = Ks[cur];
    const unsigned short* Vc = Vs[cur];
    // QK^T (swapped): A = K rows (k = mk*16+4g+j), B = Q (col q = lr)
    f32x4 st[4] = {};
    __builtin_amdgcn_s_setprio(1);
    #pragma unroll
    for (int mk = 0; mk < 4; ++mk)
      #pragma unroll
      for (int ks = 0; ks < 2; ++ks){
        bf16x8 kf = *reinterpret_cast<const bf16x8*>(
            &Kc[(mk*16 + lr)*64 + (((ks*4 + g) ^ (lr & 7)))*8]);
        st[mk] = __builtin_amdgcn_mfma_f32_16x16x32_bf16(kf, b_q[ks], st[mk], 0,0,0);
      }
    __builtin_amdgcn_s_setprio(0);
    if (!((mbits >> kt) & 1)){
      const int kk0 = kt * 64;
      #pragma unroll
      for (int mk = 0; mk < 4; ++mk)
        #pragma unroll
        for (int j = 0; j < 4; ++j){
          int kg = kk0 + mk*16 + g*4 + j;
          if (mask[mbase + (size_t)(qw + lr)*2048 + kg] == 0) st[mk][j] = -3.0e30f;
        }
    }
    // online softmax (log2 domain); v_max3-friendly reduction tree (T17)
    float x0 = fmaxf(fmaxf(st[0][0], st[0][1]), st[0][2]);
    float x1 = fmaxf(fmaxf(st[0][3], st[1][0]), st[1][1]);
    float x2 = fmaxf(fmaxf(st[1][2], st[1][3]), st[2][0]);
    float x3 = fmaxf(fmaxf(st[2][1], st[2][2]), st[2][3]);
    float x4 = fmaxf(fmaxf(st[3][0], st[3][1]), st[3][2]);
    float tm = fmaxf(fmaxf(fmaxf(x0, x1), x2), fmaxf(fmaxf(x3, x4), st[3][3]));
    tm = fmaxf(tm, __shfl_xor(tm, 16));
    tm = fmaxf(tm, __shfl_xor(tm, 32));
    float tms = tm * SC;
    if (!__all(tms <= m_run + 8.f)){   // defer-max, THR=8 (P bounded by 2^8)
      float mnew = fmaxf(m_run, tms);
      float alpha = exp2f(m_run - mnew);
      lp *= alpha;
      #pragma unroll
      for (int ne = 0; ne < 4; ++ne)
        #pragma unroll
        for (int j = 0; j < 4; ++j) acc[ne][j] *= alpha;
      m_run = mnew;
    }
    // P = exp2(S*SC - m_run); pack bf16 pairs; permlane exchange -> PV B-frags
    unsigned wrd[4][2];
    float psA = 0.f, psB = 0.f;
    #pragma unroll
    for (int mk = 0; mk < 4; ++mk){
      float p0 = exp2f(__builtin_fmaf(st[mk][0], SC, -m_run));
      float p1 = exp2f(__builtin_fmaf(st[mk][1], SC, -m_run));
      float p2 = exp2f(__builtin_fmaf(st[mk][2], SC, -m_run));
      float p3 = exp2f(__builtin_fmaf(st[mk][3], SC, -m_run));
      psA += p0 + p2; psB += p1 + p3;
      wrd[mk][0] = cvt_pk_bf16(p0, p1);
      wrd[mk][1] = cvt_pk_bf16(p2, p3);
    }
    lp += psA + psB;   // per-lane partial; reduced once at the end
    bf16x8 pw[2];
    #pragma unroll
    for (int ks = 0; ks < 2; ++ks){
      unsigned a0w = wrd[2*ks][0], b0w = wrd[2*ks+1][0];
      unsigned a1w = wrd[2*ks][1], b1w = wrd[2*ks+1][1];
      plswap32(a0w, b0w); plswap16(a0w, b0w);
      plswap32(a1w, b1w); plswap16(a1w, b1w);
      u32x4 pk = { a0w, a1w, b0w, b1w };
      pw[ks] = __builtin_bit_cast(bf16x8, pk);
    }
    // PV: ctx^T += Vt * P^T
    __builtin_amdgcn_s_setprio(1);
    #pragma unroll
    for (int ks = 0; ks < 2; ++ks)
      #pragma unroll
      for (int ne = 0; ne < 4; ++ne){
        bf16x8 vf = *reinterpret_cast<const bf16x8*>(
            &Vc[(ne*16 + lr)*64 + (((ks*4 + g) ^ (lr & 7)))*8]);
        acc[ne] = __builtin_amdgcn_mfma_f32_16x16x32_bf16(vf, pw[ks], acc[ne], 0,0,0);
      }
    __builtin_amdgcn_s_setprio(0);
    if (kt < 31){
      __syncthreads();   // drains next-tile DMA + orders buffer reuse
      cur ^= 1;
    }
  }
  #undef STAGE
  float l = lp;
  l += __shfl_xor(l, 16);
  l += __shfl_xor(l, 32);
  float inv = 1.f / l;
  int q = qw + lr;
  #pragma unroll
  for (int ne = 0; ne < 4; ++ne){
    uint2 ow;
    ow.x = cvt_pk_bf16(acc[ne][0]*inv, acc[ne][1]*inv);
    ow.y = cvt_pk_bf16(acc[ne][2]*inv, acc[ne][3]*inv);
    *reinterpret_cast<uint2*>(&ctx[((size_t)b*2048 + q)*512 + h*64 + ne*16 + g*4]) = ow;
  }
}

// ---------- LayerNorm: wave per row of 512 ----------
__global__ __launch_bounds__(256) void k_ln(
    const float* __restrict__ in, const float* __restrict__ gma, const float* __restrict__ bta,
    float* __restrict__ of, unsigned short* __restrict__ ob)
{
  const int lane = threadIdx.x & 63, wid = threadIdx.x >> 6;
  const size_t row = (size_t)blockIdx.x * 4 + wid;
  const float* x = in + row * 512;
  const int e0 = lane * 8;
  float xv[8];
  *reinterpret_cast<float4*>(&xv[0]) = *reinterpret_cast<const float4*>(x + e0);
  *reinterpret_cast<float4*>(&xv[4]) = *reinterpret_cast<const float4*>(x + e0 + 4);
  float s = 0.f, ss = 0.f;
  #pragma unroll
  for (int i = 0; i < 8; ++i){ s += xv[i]; ss += xv[i]*xv[i]; }
  #pragma unroll
  for (int o = 1; o < 64; o <<= 1){ s += __shfl_xor(s, o); ss += __shfl_xor(ss, o); }
  float mu = s * (1.f/512.f);
  float var = ss * (1.f/512.f) - mu*mu;
  float rs = rsqrtf(var + 1e-5f);
  float gv[8], bv[8], y[8];
  *reinterpret_cast<float4*>(&gv[0]) = *reinterpret_cast<const float4*>(gma + e0);
  *reinterpret_cast<float4*>(&gv[4]) = *reinterpret_cast<const float4*>(gma + e0 + 4);
  *reinterpret_cast<float4*>(&bv[0]) = *reinterpret_cast<const float4*>(bta + e0);
  *reinterpret_cast<float4*>(&bv[4]) = *reinterpret_cast<const float4*>(bta + e0 + 4);
  #pragma unroll
  for (int i = 0; i < 8; ++i) y[i] = (xv[i]-mu)*rs*gv[i] + bv[i];
  *reinterpret_cast<float4*>(of + row*512 + e0)     = *reinterpret_cast<float4*>(&y[0]);
  *reinterpret_cast<float4*>(of + row*512 + e0 + 4) = *reinterpret_cast<float4*>(&y[4]);
  if (ob){
    us4 o0 = { f2bf(y[0]), f2bf(y[1]), f2bf(y[2]), f2bf(y[3]) };
    us4 o1 = { f2bf(y[4]), f2bf(y[5]), f2bf(y[6]), f2bf(y[7]) };
    *reinterpret_cast<us4*>(ob + row*512 + e0)     = o0;
    *reinterpret_cast<us4*>(ob + row*512 + e0 + 4) = o1;
  }
}

extern "C" void kernel_launch(void* const* d_in, const int* in_sizes, int n_in,
                              void* d_out, int out_size, void* d_ws, size_t ws_size,
                              hipStream_t stream)
{
  const float* src  = (const float*)d_in[0];
  const int*   mask = (const int*)d_in[1];
  const float* q_w  = (const float*)d_in[2];
  const float* q_b  = (const float*)d_in[3];
  const float* k_w  = (const float*)d_in[4];
  const float* k_b  = (const float*)d_in[5];
  const float* v_w  = (const float*)d_in[6];
  const float* v_b  = (const float*)d_in[7];
  const float* o_w  = (const float*)d_in[8];
  const float* o_b  = (const float*)d_in[9];
  const float* ln1g = (const float*)d_in[10];
  const float* ln1b = (const float*)d_in[11];
  const float* w1   = (const float*)d_in[12];
  const float* b1   = (const float*)d_in[13];
  const float* w2   = (const float*)d_in[14];
  const float* b2   = (const float*)d_in[15];
  const float* ln2g = (const float*)d_in[16];
  const float* ln2b = (const float*)d_in[17];

  char* ws = (char*)d_ws;
  if (ws_size < 81795072) return;
  unsigned short* x_bf  = (unsigned short*)(ws + 0);          // 8.4MB (reused as LN1 bf16 out)
  unsigned short* wtqkv = (unsigned short*)(ws + 8388608);
  float*          bqkv  = (float*)(ws + 9961472);
  unsigned short* wto   = (unsigned short*)(ws + 9967616);
  unsigned short* wt1   = (unsigned short*)(ws + 10491904);
  unsigned short* wt2   = (unsigned short*)(ws + 12589056);
  unsigned short* Qb    = (unsigned short*)(ws + 14686208);
  unsigned short* Kb    = (unsigned short*)(ws + 23074816);
  unsigned short* Vt    = (unsigned short*)(ws + 31463424);
  unsigned short* ctx   = (unsigned short*)(ws + 39852032);
  unsigned short* ffb   = (unsigned short*)(ws + 14686208);   // overlays Q/K/Vt/ctx (dead by FF1)
  float* res = (float*)(ws + 48240640);                        // res1 then res2
  float* xf  = (float*)(ws + 65017856);
  unsigned short* mb16 = (unsigned short*)(ws + 48240640);     // bitmap in res head (dead by gemm<1>)
  const unsigned* mb32 = (const unsigned*)(ws + 48240640);
  float* outf = (float*)d_out;

  k_prep<<<7430, 256, 0, stream>>>(mask, src, q_w, k_w, v_w, q_b, k_b, v_b,
                                   o_w, w1, w2, mb16, x_bf, wtqkv, bqkv, wto, wt1, wt2);

  k_gemm<0><<<dim3(64,12), 256, 0, stream>>>(x_bf, wtqkv, bqkv, nullptr,
                                             Qb, Kb, Vt, nullptr, 8192, 1536, 512);
  k_attn<<<dim3(32,16), 512, 0, stream>>>(Qb, Kb, Vt, mask, mb32, ctx);
  k_gemm<1><<<dim3(64,4), 256, 0, stream>>>(ctx, wto, o_b, src,
                                            nullptr, nullptr, nullptr, res, 8192, 512, 512);
  k_ln<<<2048, 256, 0, stream>>>(res, ln1g, ln1b, xf, x_bf);
  k_gemm<2><<<dim3(64,16), 256, 0, stream>>>(x_bf, wt1, b1, nullptr,
                                             ffb, nullptr, nullptr, nullptr, 8192, 2048, 512);
  k_gemm<3><<<dim3(64,4), 256, 0, stream>>>(ffb, wt2, b2, xf,
                                            nullptr, nullptr, nullptr, res, 8192, 512, 2048);
  k_ln<<<2048, 256, 0, stream>>>(res, ln2g, ln2b, outf, nullptr);
}